// Round 1
// baseline (2908.955 us; speedup 1.0000x reference)
//
#include <hip/hip_runtime.h>
#include <math.h>

#define N_NODES 100000
#define N_EDGES 50000
#define N_NNZ   600000
#define ATS 68   // LDS row stride (floats) for transposed tiles

// ---------- helpers ----------
__device__ __forceinline__ unsigned fkey(float f){
  unsigned u = __float_as_uint(f);
  return (u & 0x80000000u) ? ~u : (u | 0x80000000u);
}
__device__ __forceinline__ float fdec(unsigned k){
  return (k & 0x80000000u) ? __uint_as_float(k ^ 0x80000000u) : __uint_as_float(~k);
}

// ---------- prep: weight folds, q/kwq, bias table, constant vectors ----------
__global__ void prepk(
  const float* __restrict__ ln1g, const float* __restrict__ ln1b,
  const float* __restrict__ m1w1, const float* __restrict__ m1b1,
  const float* __restrict__ ln2g, const float* __restrict__ ln2b,
  const float* __restrict__ m2w1, const float* __restrict__ m2b1,
  const float* __restrict__ ln3g, const float* __restrict__ ln3b,
  const float* __restrict__ m3w1, const float* __restrict__ m3b1,
  const float* __restrict__ pe2, const float* __restrict__ pe3,
  const float* __restrict__ pe_q, const float* __restrict__ qw1,
  const float* __restrict__ qb1, const float* __restrict__ qw2,
  const float* __restrict__ qb2, const float* __restrict__ kw,
  const float* __restrict__ kb,
  const float* __restrict__ pe_b, const float* __restrict__ bw1,
  const float* __restrict__ bb1, const float* __restrict__ bw2,
  const float* __restrict__ bb2,
  float* __restrict__ W1G1, float* __restrict__ W1G2, float* __restrict__ W1G3,
  float* __restrict__ u11, float* __restrict__ u12, float* __restrict__ u13,
  float* __restrict__ c1v, float* __restrict__ c2v, float* __restrict__ c20v,
  float* __restrict__ c3tab, float* __restrict__ kwq, float* __restrict__ kqb,
  float* __restrict__ biasT)
{
  const int b = blockIdx.x, tid = threadIdx.x;
  __shared__ float ps[11*256];
  if (b < 4) {
    for (int i = tid; i < 16384; i += 256) { int idx = b*16384 + i; W1G1[idx] = ln1g[idx>>8]*m1w1[idx]; }
  } else if (b < 8) {
    int bb = b-4;
    for (int i = tid; i < 16384; i += 256) { int idx = bb*16384 + i; W1G2[idx] = ln2g[idx>>8]*m2w1[idx]; }
  } else if (b < 12) {
    int bb = b-8;
    for (int i = tid; i < 16384; i += 256) { int idx = bb*16384 + i; W1G3[idx] = ln3g[idx>>8]*m3w1[idx]; }
  } else if (b == 12) {
    int c = tid; float su = 0.f, sc = 0.f;
    for (int k = 0; k < 256; k++) { float w = m1w1[k*256+c]; su += ln1g[k]*w; sc += ln1b[k]*w; }
    u11[c] = su; c1v[c] = m1b1[c] + sc;
  } else if (b == 13) {
    int c = tid; float su = 0.f, sl = 0.f, p0 = 0.f, p1 = 0.f;
    for (int k = 0; k < 256; k++) {
      float wl = m2w1[k*256+c], wh = m2w1[(256+k)*256+c];
      su += ln2g[k]*wl; sl += ln2b[k]*wl; p0 += pe2[k]*wh; p1 += pe2[256+k]*wh;
    }
    u12[c] = su; c2v[c] = m2b1[c] + sl + p1; c20v[c] = m2b1[c] + sl + p0;
  } else if (b == 14) {
    int c = tid; float su = 0.f, sl = 0.f;
    for (int k = 0; k < 256; k++) { float wl = m3w1[k*256+c]; su += ln3g[k]*wl; sl += ln3b[k]*wl; }
    u13[c] = su;
    float base3 = m3b1[c] + sl;
    for (int o = 0; o < 11; o++) {
      float acc = 0.f;
      for (int k = 0; k < 256; k++) acc += pe3[o*256+k]*m3w1[(256+k)*256+c];
      c3tab[o*256+c] = base3 + acc;
    }
  } else if (b == 15) {
    // q01 = relu(pe_q@qw1+qb1)@qw2+qb2 ; kwq = kw-folded-with-q ; kqb = kb-folded
    int j = tid;
    for (int r = 0; r < 2; r++) {
      float acc = qb1[j];
      for (int k = 0; k < 64; k++) acc += pe_q[r*64+k]*qw1[k*256+j];
      ps[r*256+j] = fmaxf(acc, 0.f);
    }
    __syncthreads();
    for (int r = 0; r < 2; r++) {
      float acc = qb2[j];
      for (int k = 0; k < 256; k++) acc += ps[r*256+k]*qw2[k*256+j];
      ps[512 + r*256 + j] = acc;
    }
    __syncthreads();
    {
      const float* q0 = &ps[512]; const float* q1 = &ps[768];
      int k = tid;
      for (int h = 0; h < 8; h++) {
        float s0 = 0.f, s1 = 0.f;
        for (int d = 0; d < 32; d++) {
          s0 += kw[k*512 + h*32 + d]       * q0[h*32+d];
          s1 += kw[k*512 + 256 + h*32 + d] * q1[h*32+d];
        }
        kwq[k*16+h]   = s0 * 0.17677669529663687f;  // 1/sqrt(32)
        kwq[k*16+8+h] = s1;
      }
      if (tid < 8) {
        float s0 = 0.f, s1 = 0.f;
        for (int d = 0; d < 32; d++) {
          s0 += kb[tid*32+d]     * q0[tid*32+d];
          s1 += kb[256+tid*32+d] * q1[tid*32+d];
        }
        kqb[tid]   = s0 * 0.17677669529663687f;
        kqb[8+tid] = s1;
      }
    }
  } else if (b == 16) {
    // bias table = relu(pe_b@bw1+bb1)@bw2+bb2  [11,256]
    int j = tid;
    for (int o = 0; o < 11; o++) {
      float acc = bb1[j];
      for (int k = 0; k < 64; k++) acc += pe_b[o*64+k]*bw1[k*256+j];
      ps[o*256+j] = fmaxf(acc, 0.f);
    }
    __syncthreads();
    int c = tid;
    for (int o = 0; o < 11; o++) {
      float acc = bb2[c];
      for (int k = 0; k < 256; k++) acc += ps[o*256+k]*bw2[k*256+c];
      biasT[o*256+c] = acc;
    }
  }
}

// ---------- init scratch ----------
__global__ void initk(int* __restrict__ cnt, float* __restrict__ P,
                      float* __restrict__ S, unsigned* __restrict__ Mkey){
  int i = blockIdx.x*256 + threadIdx.x;
  if (i < N_EDGES) cnt[i] = 0;
  if (i < 256) P[i] = 0.f;
  if (i < 8) { S[i] = 0.f; Mkey[i] = 0u; }
}

// ---------- CSR build ----------
__global__ void countk(const int* __restrict__ nidx, int* __restrict__ cnt){
  int e = blockIdx.x*256 + threadIdx.x;
  if (e < N_NNZ) { int g = nidx[e]; if (g < N_EDGES) atomicAdd(&cnt[g], 1); }
}
__global__ void scank(const int* __restrict__ cnt, int* __restrict__ offA, int* __restrict__ curA){
  __shared__ int sh[1024];
  int tid = threadIdx.x;
  const int PER = (N_EDGES + 1023)/1024;
  int base = tid*PER;
  int s = 0;
  for (int i = 0; i < PER; i++) { int idx = base+i; if (idx < N_EDGES) s += cnt[idx]; }
  sh[tid] = s;
  __syncthreads();
  for (int d = 1; d < 1024; d <<= 1) {
    int v = (tid >= d) ? sh[tid-d] : 0;
    __syncthreads();
    sh[tid] += v;
    __syncthreads();
  }
  int run = (tid == 0) ? 0 : sh[tid-1];
  for (int i = 0; i < PER; i++) {
    int idx = base+i;
    if (idx < N_EDGES) { offA[idx] = run; curA[idx] = run; run += cnt[idx]; }
  }
}
__global__ void fillk(const int* __restrict__ nidx, int* __restrict__ curA, int* __restrict__ ent){
  int e = blockIdx.x*256 + threadIdx.x;
  if (e < N_NNZ) {
    int g = nidx[e];
    if (g < N_EDGES) { int p = atomicAdd(&curA[g], 1); ent[p] = e; }
  }
}

// ---------- fused residual MLP:  dst = src + relu(rs*(src@W1 - mu*u1) + cb[row])@W2 + b2 + addv[row] ----------
__global__ __launch_bounds__(256) void mlpk(
  const float* __restrict__ src, float* __restrict__ dst, int nrows,
  const float* __restrict__ W1, const float* __restrict__ u1,
  const float* __restrict__ cb, const int* __restrict__ cidx,
  const float* __restrict__ W2, const float* __restrict__ b2,
  const float* __restrict__ addv, const int* __restrict__ aidx)
{
  __shared__ __align__(16) float at[256*ATS];
  __shared__ float2 red[256];
  __shared__ float2 rowstat[64];
  const int tid = threadIdx.x;
  const int tr = tid >> 5, tc = tid & 31;
  const int row0 = blockIdx.x * 64;

  { // stage t transposed: at[k][r^swz]
    const int k = tid, swz = k & 0x3C;
    const float* sp = src + row0*256 + k;
    #pragma unroll
    for (int bb = 0; bb < 16; bb++) {
      int r = 4*bb;
      float t0 = (row0 + r + 0 < nrows) ? sp[(r+0)*256] : 0.f;
      float t1 = (row0 + r + 1 < nrows) ? sp[(r+1)*256] : 0.f;
      float t2 = (row0 + r + 2 < nrows) ? sp[(r+2)*256] : 0.f;
      float t3 = (row0 + r + 3 < nrows) ? sp[(r+3)*256] : 0.f;
      *(float4*)&at[k*ATS + (r ^ swz)] = make_float4(t0, t1, t2, t3);
    }
  }
  __syncthreads();
  { // row stats (mu, rstd) for LN fold
    const int r = tid >> 2, q = tid & 3;
    float s = 0.f, s2 = 0.f;
    for (int k = q*64; k < q*64 + 64; k++) {
      float x = at[k*ATS + (r ^ (k & 0x3C))];
      s += x; s2 += x*x;
    }
    red[tid] = make_float2(s, s2);
  }
  __syncthreads();
  if (tid < 64) {
    float2 a = red[tid*4+0], bq = red[tid*4+1], c = red[tid*4+2], d = red[tid*4+3];
    float s = a.x + bq.x + c.x + d.x, s2 = a.y + bq.y + c.y + d.y;
    float mu = s * (1.f/256.f);
    float var = fmaxf(s2*(1.f/256.f) - mu*mu, 0.f);
    rowstat[tid] = make_float2(mu, rsqrtf(var + 1e-5f));
  }
  __syncthreads();

  float acc[8][8];
  #pragma unroll
  for (int i = 0; i < 8; i++) {
    #pragma unroll
    for (int j = 0; j < 8; j++) acc[i][j] = 0.f;
  }

  // GEMM1: t @ W1
  #pragma unroll 2
  for (int kk = 0; kk < 256; kk++) {
    const float* wr = W1 + kk*256 + tc*8;
    float4 w0 = *(const float4*)wr, w1 = *(const float4*)(wr+4);
    const int sw = kk & 0x3C;
    const float* ab = &at[kk*ATS];
    float4 a0 = *(const float4*)&ab[(tr*8)     ^ sw];
    float4 a1 = *(const float4*)&ab[(tr*8 + 4) ^ sw];
    float av[8] = {a0.x,a0.y,a0.z,a0.w,a1.x,a1.y,a1.z,a1.w};
    float wv[8] = {w0.x,w0.y,w0.z,w0.w,w1.x,w1.y,w1.z,w1.w};
    #pragma unroll
    for (int i = 0; i < 8; i++) {
      #pragma unroll
      for (int j = 0; j < 8; j++) acc[i][j] = fmaf(av[i], wv[j], acc[i][j]);
    }
  }
  __syncthreads();  // everyone done reading t from LDS

  { // epilogue 1: H = relu(rs*(acc - mu*u1) + cb_row); write H^T back into at
    float4 u0 = *(const float4*)&u1[tc*8], u4 = *(const float4*)&u1[tc*8+4];
    float uv[8] = {u0.x,u0.y,u0.z,u0.w,u4.x,u4.y,u4.z,u4.w};
    #pragma unroll
    for (int i = 0; i < 8; i++) {
      int gr = row0 + tr*8 + i;
      int ci = 0;
      if (cidx != nullptr && gr < nrows) ci = cidx[gr];
      const float* cbr = cb + ci*256 + tc*8;
      float4 cb0 = *(const float4*)cbr, cb1 = *(const float4*)(cbr+4);
      float cv[8] = {cb0.x,cb0.y,cb0.z,cb0.w,cb1.x,cb1.y,cb1.z,cb1.w};
      float2 st = rowstat[tr*8+i];
      #pragma unroll
      for (int j = 0; j < 8; j++)
        acc[i][j] = fmaxf(st.y*(acc[i][j] - st.x*uv[j]) + cv[j], 0.f);
    }
    #pragma unroll
    for (int j = 0; j < 8; j++) {
      int c = tc*8 + j, sw = c & 0x3C;
      float* ab = &at[c*ATS];
      *(float4*)&ab[(tr*8)     ^ sw] = make_float4(acc[0][j], acc[1][j], acc[2][j], acc[3][j]);
      *(float4*)&ab[(tr*8 + 4) ^ sw] = make_float4(acc[4][j], acc[5][j], acc[6][j], acc[7][j]);
    }
  }
  __syncthreads();

  // GEMM2: H @ W2
  #pragma unroll
  for (int i = 0; i < 8; i++) {
    #pragma unroll
    for (int j = 0; j < 8; j++) acc[i][j] = 0.f;
  }
  #pragma unroll 2
  for (int kk = 0; kk < 256; kk++) {
    const float* wr = W2 + kk*256 + tc*8;
    float4 w0 = *(const float4*)wr, w1 = *(const float4*)(wr+4);
    const int sw = kk & 0x3C;
    const float* ab = &at[kk*ATS];
    float4 a0 = *(const float4*)&ab[(tr*8)     ^ sw];
    float4 a1 = *(const float4*)&ab[(tr*8 + 4) ^ sw];
    float av[8] = {a0.x,a0.y,a0.z,a0.w,a1.x,a1.y,a1.z,a1.w};
    float wv[8] = {w0.x,w0.y,w0.z,w0.w,w1.x,w1.y,w1.z,w1.w};
    #pragma unroll
    for (int i = 0; i < 8; i++) {
      #pragma unroll
      for (int j = 0; j < 8; j++) acc[i][j] = fmaf(av[i], wv[j], acc[i][j]);
    }
  }

  { // epilogue 2: dst = src + acc + b2 + addv
    float4 b0 = *(const float4*)&b2[tc*8], b4 = *(const float4*)&b2[tc*8+4];
    float bv[8] = {b0.x,b0.y,b0.z,b0.w,b4.x,b4.y,b4.z,b4.w};
    #pragma unroll
    for (int i = 0; i < 8; i++) {
      int gr = row0 + tr*8 + i;
      if (gr >= nrows) continue;
      const float* tp = src + gr*256 + tc*8;
      float4 t0 = *(const float4*)tp, t1 = *(const float4*)(tp+4);
      float tv[8] = {t0.x,t0.y,t0.z,t0.w,t1.x,t1.y,t1.z,t1.w};
      float ad[8] = {0,0,0,0,0,0,0,0};
      if (addv != nullptr) {
        int ai = (aidx != nullptr) ? aidx[gr] : 0;
        const float* ap = addv + ai*256 + tc*8;
        float4 A0 = *(const float4*)ap, A1 = *(const float4*)(ap+4);
        ad[0]=A0.x; ad[1]=A0.y; ad[2]=A0.z; ad[3]=A0.w;
        ad[4]=A1.x; ad[5]=A1.y; ad[6]=A1.z; ad[7]=A1.w;
      }
      float* op = dst + gr*256 + tc*8;
      *(float4*)op     = make_float4(tv[0]+acc[i][0]+bv[0]+ad[0], tv[1]+acc[i][1]+bv[1]+ad[1],
                                     tv[2]+acc[i][2]+bv[2]+ad[2], tv[3]+acc[i][3]+bv[3]+ad[3]);
    *(float4*)(op+4) = make_float4(tv[4]+acc[i][4]+bv[4]+ad[4], tv[5]+acc[i][5]+bv[5]+ad[5],
                                     tv[6]+acc[i][6]+bv[6]+ad[6], tv[7]+acc[i][7]+bv[7]+ad[7]);
    }
  }
}

// ---------- plain GEMM + bias (v projection) ----------
__global__ __launch_bounds__(256) void gemmk(
  const float* __restrict__ src, float* __restrict__ dst, int nrows,
  const float* __restrict__ W, const float* __restrict__ bias)
{
  __shared__ __align__(16) float at[256*ATS];
  const int tid = threadIdx.x;
  const int tr = tid >> 5, tc = tid & 31;
  const int row0 = blockIdx.x * 64;
  {
    const int k = tid, swz = k & 0x3C;
    const float* sp = src + row0*256 + k;
    #pragma unroll
    for (int bb = 0; bb < 16; bb++) {
      int r = 4*bb;
      float t0 = (row0 + r + 0 < nrows) ? sp[(r+0)*256] : 0.f;
      float t1 = (row0 + r + 1 < nrows) ? sp[(r+1)*256] : 0.f;
      float t2 = (row0 + r + 2 < nrows) ? sp[(r+2)*256] : 0.f;
      float t3 = (row0 + r + 3 < nrows) ? sp[(r+3)*256] : 0.f;
      *(float4*)&at[k*ATS + (r ^ swz)] = make_float4(t0, t1, t2, t3);
    }
  }
  __syncthreads();
  float acc[8][8];
  #pragma unroll
  for (int i = 0; i < 8; i++) {
    #pragma unroll
    for (int j = 0; j < 8; j++) acc[i][j] = 0.f;
  }
  #pragma unroll 2
  for (int kk = 0; kk < 256; kk++) {
    const float* wr = W + kk*256 + tc*8;
    float4 w0 = *(const float4*)wr, w1 = *(const float4*)(wr+4);
    const int sw = kk & 0x3C;
    const float* ab = &at[kk*ATS];
    float4 a0 = *(const float4*)&ab[(tr*8)     ^ sw];
    float4 a1 = *(const float4*)&ab[(tr*8 + 4) ^ sw];
    float av[8] = {a0.x,a0.y,a0.z,a0.w,a1.x,a1.y,a1.z,a1.w};
    float wv[8] = {w0.x,w0.y,w0.z,w0.w,w1.x,w1.y,w1.z,w1.w};
    #pragma unroll
    for (int i = 0; i < 8; i++) {
      #pragma unroll
      for (int j = 0; j < 8; j++) acc[i][j] = fmaf(av[i], wv[j], acc[i][j]);
    }
  }
  float4 b0 = *(const float4*)&bias[tc*8], b4 = *(const float4*)&bias[tc*8+4];
  float bv[8] = {b0.x,b0.y,b0.z,b0.w,b4.x,b4.y,b4.z,b4.w};
  #pragma unroll
  for (int i = 0; i < 8; i++) {
    int gr = row0 + tr*8 + i;
    if (gr >= nrows) continue;
    float* op = dst + gr*256 + tc*8;
    *(float4*)op     = make_float4(acc[i][0]+bv[0], acc[i][1]+bv[1], acc[i][2]+bv[2], acc[i][3]+bv[3]);
    *(float4*)(op+4) = make_float4(acc[i][4]+bv[4], acc[i][5]+bv[5], acc[i][6]+bv[6], acc[i][7]+bv[7]);
  }
}

// ---------- narrow GEMM: logits [N,16] = x1 @ kwq + kqb ----------
__global__ __launch_bounds__(256) void logitk(
  const float* __restrict__ x1, const float* __restrict__ kwq,
  const float* __restrict__ kqb, float* __restrict__ lb)
{
  __shared__ __align__(16) float xs[16*260];
  int tid = threadIdx.x;
  int r = tid >> 4, c = tid & 15;
  int row0 = blockIdx.x * 16;
  const float* sp = x1 + (row0 + r)*256 + c*16;
  float4 L0 = *(const float4*)sp, L1 = *(const float4*)(sp+4);
  float4 L2 = *(const float4*)(sp+8), L3 = *(const float4*)(sp+12);
  float* xp = &xs[r*260 + c*16];
  *(float4*)xp = L0; *(float4*)(xp+4) = L1; *(float4*)(xp+8) = L2; *(float4*)(xp+12) = L3;
  __syncthreads();
  float acc = kqb[c];
  const float* xr = &xs[r*260];
  #pragma unroll 8
  for (int k = 0; k < 256; k++) acc = fmaf(xr[k], kwq[k*16+c], acc);
  lb[(row0 + r)*16 + c] = acc;
}

// ---------- global softmax max over N (per head) ----------
__global__ void maxk(const float* __restrict__ lb, unsigned* __restrict__ Mkey){
  float mx[8];
  #pragma unroll
  for (int h = 0; h < 8; h++) mx[h] = -INFINITY;
  for (int n = blockIdx.x*256 + threadIdx.x; n < N_NODES; n += 65536) {
    float4 a = *(const float4*)&lb[n*16];
    float4 b = *(const float4*)&lb[n*16+4];
    mx[0] = fmaxf(mx[0], a.x); mx[1] = fmaxf(mx[1], a.y);
    mx[2] = fmaxf(mx[2], a.z); mx[3] = fmaxf(mx[3], a.w);
    mx[4] = fmaxf(mx[4], b.x); mx[5] = fmaxf(mx[5], b.y);
    mx[6] = fmaxf(mx[6], b.z); mx[7] = fmaxf(mx[7], b.w);
  }
  __shared__ unsigned bm[8];
  if (threadIdx.x < 8) bm[threadIdx.x] = 0u;
  __syncthreads();
  #pragma unroll
  for (int h = 0; h < 8; h++) atomicMax(&bm[h], fkey(mx[h]));
  __syncthreads();
  if (threadIdx.x < 8) atomicMax(&Mkey[threadIdx.x], bm[threadIdx.x]);
}

// ---------- att0 numerator/denominator partials ----------
__global__ void sumk(const float* __restrict__ lb, const float* __restrict__ v,
                     const unsigned* __restrict__ Mkey,
                     float* __restrict__ P, float* __restrict__ S)
{
  int tid = threadIdx.x; int h = tid >> 5;
  float Mh = fdec(Mkey[h]);
  float pa = 0.f, sa = 0.f;
  for (int n = blockIdx.x; n < N_NODES; n += gridDim.x) {
    float w = expf(lb[n*16 + h] - Mh);
    pa = fmaf(w, v[n*256 + tid], pa);
    sa += w;
  }
  atomicAdd(&P[tid], pa);
  if ((tid & 31) == 0) atomicAdd(&S[h], sa);
}

// ---------- PMA segment softmax + weighted V aggregation (wave per segment) ----------
__global__ __launch_bounds__(256) void aggk(
  const int* __restrict__ offA, const int* __restrict__ cnt,
  const int* __restrict__ ent, const int* __restrict__ eidx,
  const float* __restrict__ lb, const float* __restrict__ v,
  float* __restrict__ out)
{
  int g = blockIdx.x*4 + (threadIdx.x >> 6);
  if (g >= N_EDGES) return;
  int lane = threadIdx.x & 63;
  int h = lane >> 3;
  int co = lane*4;
  int base = offA[g], n = cnt[g];
  float m = -INFINITY, s = 0.f;
  float ax = 0.f, ay = 0.f, az = 0.f, aw = 0.f;
  for (int i = 0; i < n; i++) {
    int src = eidx[ent[base + i]];
    float ar = lb[src*16 + 8 + h];
    float a = (ar > 0.f) ? ar : 0.2f*ar;
    float mn = fmaxf(m, a);
    float sc = expf(m - mn);
    float p  = expf(a - mn);
    s = s*sc + p;
    const float4 vv = *(const float4*)(v + src*256 + co);
    ax = ax*sc + p*vv.x; ay = ay*sc + p*vv.y;
    az = az*sc + p*vv.z; aw = aw*sc + p*vv.w;
    m = mn;
  }
  float inv = 1.f/(s + 1e-16f);
  *(float4*)(out + g*256 + co) = make_float4(ax*inv, ay*inv, az*inv, aw*inv);
}

// ---------- finalize att0 and apply blk2 to the single att0 row ----------
__global__ void att0k(const float* __restrict__ P, const float* __restrict__ S,
                      const float* __restrict__ c20, const float* __restrict__ W1G2,
                      const float* __restrict__ m2w2, const float* __restrict__ m2b2,
                      float* __restrict__ att0b)
{
  __shared__ float a0[256], zs[256], Hs[256];
  __shared__ float part[4];
  __shared__ float stat[2];
  int c = threadIdx.x;
  float av = P[c] / S[c >> 5];
  a0[c] = av;
  float x = av;
  for (int o = 32; o > 0; o >>= 1) x += __shfl_down(x, o);
  if ((c & 63) == 0) part[c >> 6] = x;
  __syncthreads();
  if (c == 0) stat[0] = (part[0]+part[1]+part[2]+part[3])*(1.f/256.f);
  __syncthreads();
  float mu = stat[0];
  float d = av - mu;
  x = d*d;
  for (int o = 32; o > 0; o >>= 1) x += __shfl_down(x, o);
  if ((c & 63) == 0) part[c >> 6] = x;
  __syncthreads();
  if (c == 0) stat[1] = rsqrtf((part[0]+part[1]+part[2]+part[3])*(1.f/256.f) + 1e-5f);
  __syncthreads();
  zs[c] = (av - mu)*stat[1];
  __syncthreads();
  float acc = c20[c];
  for (int k = 0; k < 256; k++) acc = fmaf(zs[k], W1G2[k*256 + c], acc);
  Hs[c] = fmaxf(acc, 0.f);
  __syncthreads();
  float acc2 = m2b2[c];
  for (int k = 0; k < 256; k++) acc2 = fmaf(Hs[k], m2w2[k*256 + c], acc2);
  att0b[c] = a0[c] + acc2;
}

// ---------- launcher ----------
extern "C" void kernel_launch(void* const* d_in, const int* in_sizes, int n_in,
                              void* d_out, int out_size, void* d_ws, size_t ws_size,
                              hipStream_t stream)
{
  const float* x    = (const float*)d_in[0];
  const int*   nidx = (const int*)d_in[1];
  const int*   eidx = (const int*)d_in[2];
  const int*   eord = (const int*)d_in[3];
  const float* pe_q = (const float*)d_in[4];
  const float* qw1  = (const float*)d_in[5];
  const float* qb1  = (const float*)d_in[6];
  const float* qw2  = (const float*)d_in[7];
  const float* qb2  = (const float*)d_in[8];
  const float* kw   = (const float*)d_in[9];
  const float* kb   = (const float*)d_in[10];
  const float* vw   = (const float*)d_in[11];
  const float* vb   = (const float*)d_in[12];
  const float* m1w1 = (const float*)d_in[13];
  const float* m1b1 = (const float*)d_in[14];
  const float* m1w2 = (const float*)d_in[15];
  const float* m1b2 = (const float*)d_in[16];
  const float* m2w1 = (const float*)d_in[17];
  const float* m2b1 = (const float*)d_in[18];
  const float* m2w2 = (const float*)d_in[19];
  const float* m2b2 = (const float*)d_in[20];
  const float* m3w1 = (const float*)d_in[21];
  const float* m3b1 = (const float*)d_in[22];
  const float* m3w2 = (const float*)d_in[23];
  const float* m3b2 = (const float*)d_in[24];
  const float* ln1g = (const float*)d_in[25];
  const float* ln1b = (const float*)d_in[26];
  const float* ln2g = (const float*)d_in[27];
  const float* ln2b = (const float*)d_in[28];
  const float* ln3g = (const float*)d_in[29];
  const float* ln3b = (const float*)d_in[30];
  const float* pe2  = (const float*)d_in[31];
  const float* pe3  = (const float*)d_in[32];
  const float* pe_b = (const float*)d_in[33];
  const float* bw1  = (const float*)d_in[34];
  const float* bb1  = (const float*)d_in[35];
  const float* bw2  = (const float*)d_in[36];
  const float* bb2  = (const float*)d_in[37];

  float* out_v = (float*)d_out;                       // [N,256] (also x1 scratch)
  float* out_e = out_v + (size_t)N_NODES*256;         // [E,256] (also raw att1_e)

  float* ws = (float*)d_ws;
  size_t o = 0;
  float* v     = ws + o; o += (size_t)N_NODES*256;
  float* lb    = ws + o; o += (size_t)N_NODES*16;     // [N,16]: cols 0-7 logit0, 8-15 alpha_r
  float* W1G1  = ws + o; o += 65536;
  float* W1G2  = ws + o; o += 65536;
  float* W1G3  = ws + o; o += 65536;
  float* kwq   = ws + o; o += 4096;
  float* kqb   = ws + o; o += 256;
  float* biasT = ws + o; o += 11*256;
  float* u11   = ws + o; o += 256;
  float* u12   = ws + o; o += 256;
  float* u13   = ws + o; o += 256;
  float* c1v   = ws + o; o += 256;
  float* c2v   = ws + o; o += 256;
  float* c20v  = ws + o; o += 256;
  float* c3tab = ws + o; o += 11*256;
  float* att0b = ws + o; o += 256;
  float* Pacc  = ws + o; o += 256;
  float* Sacc  = ws + o; o += 256;
  unsigned* Mkey = (unsigned*)(ws + o); o += 256;
  int* cnt  = (int*)(ws + o); o += N_EDGES;
  int* offA = (int*)(ws + o); o += N_EDGES;
  int* curA = (int*)(ws + o); o += N_EDGES;
  int* ent  = (int*)(ws + o); o += N_NNZ;
  (void)in_sizes; (void)n_in; (void)out_size; (void)ws_size;

  const int GN = (N_NODES + 63)/64;   // 1563
  const int GE = (N_EDGES + 63)/64;   // 782

  prepk<<<17, 256, 0, stream>>>(ln1g, ln1b, m1w1, m1b1, ln2g, ln2b, m2w1, m2b1,
                                ln3g, ln3b, m3w1, m3b1, pe2, pe3,
                                pe_q, qw1, qb1, qw2, qb2, kw, kb,
                                pe_b, bw1, bb1, bw2, bb2,
                                W1G1, W1G2, W1G3, u11, u12, u13,
                                c1v, c2v, c20v, c3tab, kwq, kqb, biasT);
  initk<<<196, 256, 0, stream>>>(cnt, Pacc, Sacc, Mkey);
  countk<<<(N_NNZ + 255)/256, 256, 0, stream>>>(nidx, cnt);

  // x1 = x + MLP1(LN1(x))   -> out_v region
  mlpk<<<GN, 256, 0, stream>>>(x, out_v, N_NODES, W1G1, u11, c1v, nullptr,
                               m1w2, m1b2, nullptr, nullptr);
  // v = x1@vw + vb
  gemmk<<<GN, 256, 0, stream>>>(out_v, v, N_NODES, vw, vb);
  // logits [N,16] = x1@kwq + kqb
  logitk<<<N_NODES/16, 256, 0, stream>>>(out_v, kwq, kqb, lb);

  maxk<<<256, 256, 0, stream>>>(lb, Mkey);
  sumk<<<1024, 256, 0, stream>>>(lb, v, Mkey, Pacc, Sacc);

  scank<<<1, 1024, 0, stream>>>(cnt, offA, curA);
  fillk<<<(N_NNZ + 255)/256, 256, 0, stream>>>(nidx, curA, ent);
  aggk<<<N_EDGES/4, 256, 0, stream>>>(offA, cnt, ent, eidx, lb, v, out_e);

  att0k<<<1, 256, 0, stream>>>(Pacc, Sacc, c20v, W1G2, m2w2, m2b2, att0b);

  // node path: blk2 (+att0b) then blk3 (+bias[1])
  mlpk<<<GN, 256, 0, stream>>>(v, out_v, N_NODES, W1G2, u12, c2v, nullptr,
                               m2w2, m2b2, att0b, nullptr);
  mlpk<<<GN, 256, 0, stream>>>(out_v, out_v, N_NODES, W1G3, u13, c3tab + 256, nullptr,
                               m3w2, m3b2, biasT + 256, nullptr);
  // edge path: blk2 (+att0b) then blk3 with per-order c3/bias
  mlpk<<<GE, 256, 0, stream>>>(out_e, out_e, N_EDGES, W1G2, u12, c2v, nullptr,
                               m2w2, m2b2, att0b, nullptr);
  mlpk<<<GE, 256, 0, stream>>>(out_e, out_e, N_EDGES, W1G3, u13, c3tab, eord,
                               m3w2, m3b2, biasT, eord);
}

// Round 3
// 1512.147 us; speedup vs baseline: 1.9237x; 1.9237x over previous
//
#include <hip/hip_runtime.h>
#include <math.h>

#define N_NODES 100000
#define N_EDGES 50000
#define N_NNZ   600000

typedef __attribute__((ext_vector_type(8))) short bf16x8;
typedef __attribute__((ext_vector_type(4))) float f32x4;

// ---------- helpers ----------
__device__ __forceinline__ unsigned fkey(float f){
  unsigned u = __float_as_uint(f);
  return (u & 0x80000000u) ? ~u : (u | 0x80000000u);
}
__device__ __forceinline__ float fdec(unsigned k){
  return (k & 0x80000000u) ? __uint_as_float(k ^ 0x80000000u) : __uint_as_float(~k);
}
__device__ __forceinline__ short f2bf(float f){
  unsigned u = __float_as_uint(f);
  unsigned r = u + 0x7FFFu + ((u >> 16) & 1u);   // RNE
  return (short)(r >> 16);
}

// ---------- prep: weight folds, q/kwq, bias table, constant vectors ----------
__global__ void prepk(
  const float* __restrict__ ln1g, const float* __restrict__ ln1b,
  const float* __restrict__ m1w1, const float* __restrict__ m1b1,
  const float* __restrict__ ln2g, const float* __restrict__ ln2b,
  const float* __restrict__ m2w1, const float* __restrict__ m2b1,
  const float* __restrict__ ln3g, const float* __restrict__ ln3b,
  const float* __restrict__ m3w1, const float* __restrict__ m3b1,
  const float* __restrict__ pe2, const float* __restrict__ pe3,
  const float* __restrict__ pe_q, const float* __restrict__ qw1,
  const float* __restrict__ qb1, const float* __restrict__ qw2,
  const float* __restrict__ qb2, const float* __restrict__ kw,
  const float* __restrict__ kb,
  const float* __restrict__ pe_b, const float* __restrict__ bw1,
  const float* __restrict__ bb1, const float* __restrict__ bw2,
  const float* __restrict__ bb2,
  float* __restrict__ W1G1, float* __restrict__ W1G2, float* __restrict__ W1G3,
  float* __restrict__ u11, float* __restrict__ u12, float* __restrict__ u13,
  float* __restrict__ c1v, float* __restrict__ c2v, float* __restrict__ c20v,
  float* __restrict__ c3tab, float* __restrict__ kwq, float* __restrict__ kqb,
  float* __restrict__ biasT)
{
  const int b = blockIdx.x, tid = threadIdx.x;
  __shared__ float ps[11*256];
  if (b < 4) {
    for (int i = tid; i < 16384; i += 256) { int idx = b*16384 + i; W1G1[idx] = ln1g[idx>>8]*m1w1[idx]; }
  } else if (b < 8) {
    int bb = b-4;
    for (int i = tid; i < 16384; i += 256) { int idx = bb*16384 + i; W1G2[idx] = ln2g[idx>>8]*m2w1[idx]; }
  } else if (b < 12) {
    int bb = b-8;
    for (int i = tid; i < 16384; i += 256) { int idx = bb*16384 + i; W1G3[idx] = ln3g[idx>>8]*m3w1[idx]; }
  } else if (b == 12) {
    int c = tid; float su = 0.f, sc = 0.f;
    for (int k = 0; k < 256; k++) { float w = m1w1[k*256+c]; su += ln1g[k]*w; sc += ln1b[k]*w; }
    u11[c] = su; c1v[c] = m1b1[c] + sc;
  } else if (b == 13) {
    int c = tid; float su = 0.f, sl = 0.f, p0 = 0.f, p1 = 0.f;
    for (int k = 0; k < 256; k++) {
      float wl = m2w1[k*256+c], wh = m2w1[(256+k)*256+c];
      su += ln2g[k]*wl; sl += ln2b[k]*wl; p0 += pe2[k]*wh; p1 += pe2[256+k]*wh;
    }
    u12[c] = su; c2v[c] = m2b1[c] + sl + p1; c20v[c] = m2b1[c] + sl + p0;
  } else if (b == 14) {
    int c = tid; float su = 0.f, sl = 0.f;
    for (int k = 0; k < 256; k++) { float wl = m3w1[k*256+c]; su += ln3g[k]*wl; sl += ln3b[k]*wl; }
    u13[c] = su;
    float base3 = m3b1[c] + sl;
    for (int o = 0; o < 11; o++) {
      float acc = 0.f;
      for (int k = 0; k < 256; k++) acc += pe3[o*256+k]*m3w1[(256+k)*256+c];
      c3tab[o*256+c] = base3 + acc;
    }
  } else if (b == 15) {
    int j = tid;
    for (int r = 0; r < 2; r++) {
      float acc = qb1[j];
      for (int k = 0; k < 64; k++) acc += pe_q[r*64+k]*qw1[k*256+j];
      ps[r*256+j] = fmaxf(acc, 0.f);
    }
    __syncthreads();
    for (int r = 0; r < 2; r++) {
      float acc = qb2[j];
      for (int k = 0; k < 256; k++) acc += ps[r*256+k]*qw2[k*256+j];
      ps[512 + r*256 + j] = acc;
    }
    __syncthreads();
    {
      const float* q0 = &ps[512]; const float* q1 = &ps[768];
      int k = tid;
      for (int h = 0; h < 8; h++) {
        float s0 = 0.f, s1 = 0.f;
        for (int d = 0; d < 32; d++) {
          s0 += kw[k*512 + h*32 + d]       * q0[h*32+d];
          s1 += kw[k*512 + 256 + h*32 + d] * q1[h*32+d];
        }
        kwq[k*16+h]   = s0 * 0.17677669529663687f;  // 1/sqrt(32)
        kwq[k*16+8+h] = s1;
      }
      if (tid < 8) {
        float s0 = 0.f, s1 = 0.f;
        for (int d = 0; d < 32; d++) {
          s0 += kb[tid*32+d]     * q0[tid*32+d];
          s1 += kb[256+tid*32+d] * q1[tid*32+d];
        }
        kqb[tid]   = s0 * 0.17677669529663687f;
        kqb[8+tid] = s1;
      }
    }
  } else if (b == 16) {
    int j = tid;
    for (int o = 0; o < 11; o++) {
      float acc = bb1[j];
      for (int k = 0; k < 64; k++) acc += pe_b[o*64+k]*bw1[k*256+j];
      ps[o*256+j] = fmaxf(acc, 0.f);
    }
    __syncthreads();
    int c = tid;
    for (int o = 0; o < 11; o++) {
      float acc = bb2[c];
      for (int k = 0; k < 256; k++) acc += ps[o*256+k]*bw2[k*256+c];
      biasT[o*256+c] = acc;
    }
  }
}

// ---------- pack fp32 [k][n] -> bf16 [n][k] (transposed, MFMA B-operand friendly) ----------
__global__ void packk(const float* __restrict__ s0, const float* __restrict__ s1,
                      const float* __restrict__ s2, const float* __restrict__ s3,
                      const float* __restrict__ s4, const float* __restrict__ s5,
                      const float* __restrict__ s6, short* __restrict__ dst)
{
  const float* srcs[7] = {s0,s1,s2,s3,s4,s5,s6};
  const float* S = srcs[blockIdx.y];
  short* D = dst + (size_t)blockIdx.y*65536;
  int n = threadIdx.x;
  int k0 = blockIdx.x*32;
  short vb[32];
  #pragma unroll
  for (int i = 0; i < 32; i++) vb[i] = f2bf(S[(k0+i)*256 + n]);
  #pragma unroll
  for (int i = 0; i < 4; i++) *(bf16x8*)&D[n*256 + k0 + i*8] = *(bf16x8*)&vb[i*8];
}

// ---------- init scratch ----------
__global__ void initk(int* __restrict__ cnt, float* __restrict__ P,
                      float* __restrict__ S, unsigned* __restrict__ Mkey){
  int i = blockIdx.x*256 + threadIdx.x;
  if (i < N_EDGES) cnt[i] = 0;
  if (i < 256) P[i] = 0.f;
  if (i < 8) { S[i] = 0.f; Mkey[i] = 0u; }
}

// ---------- CSR build ----------
__global__ void countk(const int* __restrict__ nidx, int* __restrict__ cnt){
  int e = blockIdx.x*256 + threadIdx.x;
  if (e < N_NNZ) { int g = nidx[e]; if (g < N_EDGES) atomicAdd(&cnt[g], 1); }
}
__global__ void scank(const int* __restrict__ cnt, int* __restrict__ offA, int* __restrict__ curA){
  __shared__ int sh[1024];
  int tid = threadIdx.x;
  const int PER = (N_EDGES + 1023)/1024;
  int base = tid*PER;
  int s = 0;
  for (int i = 0; i < PER; i++) { int idx = base+i; if (idx < N_EDGES) s += cnt[idx]; }
  sh[tid] = s;
  __syncthreads();
  for (int d = 1; d < 1024; d <<= 1) {
    int v = (tid >= d) ? sh[tid-d] : 0;
    __syncthreads();
    sh[tid] += v;
    __syncthreads();
  }
  int run = (tid == 0) ? 0 : sh[tid-1];
  for (int i = 0; i < PER; i++) {
    int idx = base+i;
    if (idx < N_EDGES) { offA[idx] = run; curA[idx] = run; run += cnt[idx]; }
  }
}
__global__ void fillk(const int* __restrict__ nidx, int* __restrict__ curA, int* __restrict__ ent){
  int e = blockIdx.x*256 + threadIdx.x;
  if (e < N_NNZ) {
    int g = nidx[e];
    if (g < N_EDGES) { int p = atomicAdd(&curA[g], 1); ent[p] = e; }
  }
}

// ---------- fused residual MLP (MFMA): dst = src + relu(rs*(src@W1 - mu*u1) + cb[row])@W2 + b2 + addv[row] ----------
__global__ __launch_bounds__(256, 3) void mlpk(
  const float* __restrict__ src, float* __restrict__ dst, int nrows,
  const short* __restrict__ Wp1, const float* __restrict__ u1,
  const float* __restrict__ cb, const int* __restrict__ cidx,
  const short* __restrict__ Wp2, const float* __restrict__ b2,
  const float* __restrict__ addv, const int* __restrict__ aidx)
{
  __shared__ __align__(16) short tile[64*256];   // bf16, swizzled
  __shared__ float2 red[256];
  __shared__ float2 rowstat[64];
  char* tb = (char*)tile;
  const int tid = threadIdx.x;
  const int wv = tid >> 6, lane = tid & 63;
  const int lr = lane & 15;            // frag row (A) / col (B,D)
  const int lk = (lane >> 4) * 8;      // frag k offset
  const int rb = (lane >> 4) * 4;      // D frag row base
  const int row0 = blockIdx.x * 64;
  const int swzA = (lr & 7) << 4;

  { // stage src -> bf16 LDS (swizzled), accumulate row stats in f32
    int row = tid >> 2;
    int c0  = (tid & 3) * 64;
    bool ok = (row0 + row < nrows);
    const float* sp = src + (size_t)(row0 + row)*256 + c0;
    float s = 0.f, s2 = 0.f;
    int swz = (row & 7) << 4;
    #pragma unroll
    for (int j = 0; j < 8; j++) {
      float4 f0 = ok ? *(const float4*)(sp + j*8)     : make_float4(0,0,0,0);
      float4 f1 = ok ? *(const float4*)(sp + j*8 + 4) : make_float4(0,0,0,0);
      s += f0.x+f0.y+f0.z+f0.w + f1.x+f1.y+f1.z+f1.w;
      s2 += f0.x*f0.x+f0.y*f0.y+f0.z*f0.z+f0.w*f0.w + f1.x*f1.x+f1.y*f1.y+f1.z*f1.z+f1.w*f1.w;
      bf16x8 h;
      h[0]=f2bf(f0.x); h[1]=f2bf(f0.y); h[2]=f2bf(f0.z); h[3]=f2bf(f0.w);
      h[4]=f2bf(f1.x); h[5]=f2bf(f1.y); h[6]=f2bf(f1.z); h[7]=f2bf(f1.w);
      int k = c0 + j*8;
      *(bf16x8*)(tb + ((row*512 + k*2) ^ swz)) = h;
    }
    red[tid] = make_float2(s, s2);
  }
  __syncthreads();
  if (tid < 64) {
    float2 A = red[tid*4+0], B = red[tid*4+1], C = red[tid*4+2], D = red[tid*4+3];
    float s = A.x+B.x+C.x+D.x, s2 = A.y+B.y+C.y+D.y;
    float mu = s * (1.f/256.f);
    float var = fmaxf(s2*(1.f/256.f) - mu*mu, 0.f);
    rowstat[tid] = make_float2(mu, rsqrtf(var + 1e-5f));
  }
  __syncthreads();

  const f32x4 zero = {0.f, 0.f, 0.f, 0.f};
  f32x4 acc[4][4];
  #pragma unroll
  for (int rt = 0; rt < 4; rt++)
    #pragma unroll
    for (int ct = 0; ct < 4; ct++) acc[rt][ct] = zero;

  const short* wb1[4];
  #pragma unroll
  for (int ct = 0; ct < 4; ct++) wb1[ct] = Wp1 + (wv*64 + ct*16 + lr)*256 + lk;

  // GEMM1
  #pragma unroll
  for (int ks = 0; ks < 8; ks++) {
    bf16x8 a[4], b[4];
    #pragma unroll
    for (int rt = 0; rt < 4; rt++)
      a[rt] = *(const bf16x8*)(tb + (((rt*16 + lr)*512 + ks*64 + lk*2) ^ swzA));
    #pragma unroll
    for (int ct = 0; ct < 4; ct++)
      b[ct] = *(const bf16x8*)(wb1[ct] + ks*32);
    #pragma unroll
    for (int rt = 0; rt < 4; rt++)
      #pragma unroll
      for (int ct = 0; ct < 4; ct++)
        acc[rt][ct] = __builtin_amdgcn_mfma_f32_16x16x32_bf16(a[rt], b[ct], acc[rt][ct], 0, 0, 0);
  }
  __syncthreads();   // all waves done reading the src tile

  { // epilogue 1: H = relu(rs*(acc - mu*u1) + cb[cidx[row]]); write bf16 H back (swizzled)
    float u1v[4];
    #pragma unroll
    for (int ct = 0; ct < 4; ct++) u1v[ct] = u1[wv*64 + ct*16 + lr];
    #pragma unroll
    for (int rt = 0; rt < 4; rt++) {
      #pragma unroll
      for (int r = 0; r < 4; r++) {
        int rl = rt*16 + rb + r;
        float2 st = rowstat[rl];
        int cbase = 0;
        if (cidx != nullptr) {
          int gr = row0 + rl;
          cbase = ((gr < nrows) ? cidx[gr] : 0) * 256;
        }
        int swz = (rl & 7) << 4;
        #pragma unroll
        for (int ct = 0; ct < 4; ct++) {
          int j = wv*64 + ct*16 + lr;
          float h = fmaxf(st.y*(acc[rt][ct][r] - st.x*u1v[ct]) + cb[cbase + j], 0.f);
          *(short*)(tb + ((rl*512 + j*2) ^ swz)) = f2bf(h);
        }
      }
    }
  }
  __syncthreads();

  #pragma unroll
  for (int rt = 0; rt < 4; rt++)
    #pragma unroll
    for (int ct = 0; ct < 4; ct++) acc[rt][ct] = zero;

  const short* wb2[4];
  #pragma unroll
  for (int ct = 0; ct < 4; ct++) wb2[ct] = Wp2 + (wv*64 + ct*16 + lr)*256 + lk;

  // GEMM2
  #pragma unroll
  for (int ks = 0; ks < 8; ks++) {
    bf16x8 a[4], b[4];
    #pragma unroll
    for (int rt = 0; rt < 4; rt++)
      a[rt] = *(const bf16x8*)(tb + (((rt*16 + lr)*512 + ks*64 + lk*2) ^ swzA));
    #pragma unroll
    for (int ct = 0; ct < 4; ct++)
      b[ct] = *(const bf16x8*)(wb2[ct] + ks*32);
    #pragma unroll
    for (int rt = 0; rt < 4; rt++)
      #pragma unroll
      for (int ct = 0; ct < 4; ct++)
        acc[rt][ct] = __builtin_amdgcn_mfma_f32_16x16x32_bf16(a[rt], b[ct], acc[rt][ct], 0, 0, 0);
  }

  { // epilogue 2: dst = src + acc + b2 + addv[aidx[row]]
    float b2v[4];
    #pragma unroll
    for (int ct = 0; ct < 4; ct++) b2v[ct] = b2[wv*64 + ct*16 + lr];
    #pragma unroll
    for (int rt = 0; rt < 4; rt++) {
      #pragma unroll
      for (int r = 0; r < 4; r++) {
        int rl = rt*16 + rb + r;
        int gr = row0 + rl;
        if (gr >= nrows) continue;
        int abase = (aidx != nullptr) ? aidx[gr]*256 : 0;
        #pragma unroll
        for (int ct = 0; ct < 4; ct++) {
          int j = wv*64 + ct*16 + lr;
          float o = src[(size_t)gr*256 + j] + acc[rt][ct][r] + b2v[ct];
          if (addv != nullptr) o += addv[abase + j];
          dst[(size_t)gr*256 + j] = o;
        }
      }
    }
  }
}

// ---------- plain GEMM + bias (MFMA, v projection) ----------
__global__ __launch_bounds__(256, 3) void gemmk(
  const float* __restrict__ src, float* __restrict__ dst, int nrows,
  const short* __restrict__ Wp, const float* __restrict__ bias)
{
  __shared__ __align__(16) short tile[64*256];
  char* tb = (char*)tile;
  const int tid = threadIdx.x;
  const int wv = tid >> 6, lane = tid & 63;
  const int lr = lane & 15;
  const int lk = (lane >> 4) * 8;
  const int rb = (lane >> 4) * 4;
  const int row0 = blockIdx.x * 64;
  const int swzA = (lr & 7) << 4;

  {
    int row = tid >> 2;
    int c0  = (tid & 3) * 64;
    bool ok = (row0 + row < nrows);
    const float* sp = src + (size_t)(row0 + row)*256 + c0;
    int swz = (row & 7) << 4;
    #pragma unroll
    for (int j = 0; j < 8; j++) {
      float4 f0 = ok ? *(const float4*)(sp + j*8)     : make_float4(0,0,0,0);
      float4 f1 = ok ? *(const float4*)(sp + j*8 + 4) : make_float4(0,0,0,0);
      bf16x8 h;
      h[0]=f2bf(f0.x); h[1]=f2bf(f0.y); h[2]=f2bf(f0.z); h[3]=f2bf(f0.w);
      h[4]=f2bf(f1.x); h[5]=f2bf(f1.y); h[6]=f2bf(f1.z); h[7]=f2bf(f1.w);
      int k = c0 + j*8;
      *(bf16x8*)(tb + ((row*512 + k*2) ^ swz)) = h;
    }
  }
  __syncthreads();

  const f32x4 zero = {0.f, 0.f, 0.f, 0.f};
  f32x4 acc[4][4];
  #pragma unroll
  for (int rt = 0; rt < 4; rt++)
    #pragma unroll
    for (int ct = 0; ct < 4; ct++) acc[rt][ct] = zero;

  const short* wb[4];
  #pragma unroll
  for (int ct = 0; ct < 4; ct++) wb[ct] = Wp + (wv*64 + ct*16 + lr)*256 + lk;

  #pragma unroll
  for (int ks = 0; ks < 8; ks++) {
    bf16x8 a[4], b[4];
    #pragma unroll
    for (int rt = 0; rt < 4; rt++)
      a[rt] = *(const bf16x8*)(tb + (((rt*16 + lr)*512 + ks*64 + lk*2) ^ swzA));
    #pragma unroll
    for (int ct = 0; ct < 4; ct++)
      b[ct] = *(const bf16x8*)(wb[ct] + ks*32);
    #pragma unroll
    for (int rt = 0; rt < 4; rt++)
      #pragma unroll
      for (int ct = 0; ct < 4; ct++)
        acc[rt][ct] = __builtin_amdgcn_mfma_f32_16x16x32_bf16(a[rt], b[ct], acc[rt][ct], 0, 0, 0);
  }

  {
    float bv[4];
    #pragma unroll
    for (int ct = 0; ct < 4; ct++) bv[ct] = bias[wv*64 + ct*16 + lr];
    #pragma unroll
    for (int rt = 0; rt < 4; rt++) {
      #pragma unroll
      for (int r = 0; r < 4; r++) {
        int rl = rt*16 + rb + r;
        int gr = row0 + rl;
        if (gr >= nrows) continue;
        #pragma unroll
        for (int ct = 0; ct < 4; ct++) {
          int j = wv*64 + ct*16 + lr;
          dst[(size_t)gr*256 + j] = acc[rt][ct][r] + bv[ct];
        }
      }
    }
  }
}

// ---------- narrow GEMM: logits [N,16] = x1 @ kwq + kqb ----------
__global__ __launch_bounds__(256) void logitk(
  const float* __restrict__ x1, const float* __restrict__ kwq,
  const float* __restrict__ kqb, float* __restrict__ lb)
{
  __shared__ __align__(16) float xs[16*260];
  int tid = threadIdx.x;
  int r = tid >> 4, c = tid & 15;
  int row0 = blockIdx.x * 16;
  const float* sp = x1 + (row0 + r)*256 + c*16;
  float4 L0 = *(const float4*)sp, L1 = *(const float4*)(sp+4);
  float4 L2 = *(const float4*)(sp+8), L3 = *(const float4*)(sp+12);
  float* xp = &xs[r*260 + c*16];
  *(float4*)xp = L0; *(float4*)(xp+4) = L1; *(float4*)(xp+8) = L2; *(float4*)(xp+12) = L3;
  __syncthreads();
  float acc = kqb[c];
  const float* xr = &xs[r*260];
  #pragma unroll 8
  for (int k = 0; k < 256; k++) acc = fmaf(xr[k], kwq[k*16+c], acc);
  lb[(row0 + r)*16 + c] = acc;
}

// ---------- global softmax max over N (per head) ----------
__global__ void maxk(const float* __restrict__ lb, unsigned* __restrict__ Mkey){
  float mx[8];
  #pragma unroll
  for (int h = 0; h < 8; h++) mx[h] = -INFINITY;
  for (int n = blockIdx.x*256 + threadIdx.x; n < N_NODES; n += 65536) {
    float4 a = *(const float4*)&lb[n*16];
    float4 b = *(const float4*)&lb[n*16+4];
    mx[0] = fmaxf(mx[0], a.x); mx[1] = fmaxf(mx[1], a.y);
    mx[2] = fmaxf(mx[2], a.z); mx[3] = fmaxf(mx[3], a.w);
    mx[4] = fmaxf(mx[4], b.x); mx[5] = fmaxf(mx[5], b.y);
    mx[6] = fmaxf(mx[6], b.z); mx[7] = fmaxf(mx[7], b.w);
  }
  __shared__ unsigned bm[8];
  if (threadIdx.x < 8) bm[threadIdx.x] = 0u;
  __syncthreads();
  #pragma unroll
  for (int h = 0; h < 8; h++) atomicMax(&bm[h], fkey(mx[h]));
  __syncthreads();
  if (threadIdx.x < 8) atomicMax(&Mkey[threadIdx.x], bm[threadIdx.x]);
}

// ---------- att0 numerator/denominator partials ----------
__global__ void sumk(const float* __restrict__ lb, const float* __restrict__ v,
                     const unsigned* __restrict__ Mkey,
                     float* __restrict__ P, float* __restrict__ S)
{
  int tid = threadIdx.x; int h = tid >> 5;
  float Mh = fdec(Mkey[h]);
  float pa = 0.f, sa = 0.f;
  for (int n = blockIdx.x; n < N_NODES; n += gridDim.x) {
    float w = expf(lb[n*16 + h] - Mh);
    pa = fmaf(w, v[n*256 + tid], pa);
    sa += w;
  }
  atomicAdd(&P[tid], pa);
  if ((tid & 31) == 0) atomicAdd(&S[h], sa);
}

// ---------- PMA segment softmax + weighted V aggregation (wave per segment) ----------
__global__ __launch_bounds__(256) void aggk(
  const int* __restrict__ offA, const int* __restrict__ cnt,
  const int* __restrict__ ent, const int* __restrict__ eidx,
  const float* __restrict__ lb, const float* __restrict__ v,
  float* __restrict__ out)
{
  int g = blockIdx.x*4 + (threadIdx.x >> 6);
  if (g >= N_EDGES) return;
  int lane = threadIdx.x & 63;
  int h = lane >> 3;
  int co = lane*4;
  int base = offA[g], n = cnt[g];
  float m = -INFINITY, s = 0.f;
  float ax = 0.f, ay = 0.f, az = 0.f, aw = 0.f;
  for (int i = 0; i < n; i++) {
    int src = eidx[ent[base + i]];
    float ar = lb[src*16 + 8 + h];
    float a = (ar > 0.f) ? ar : 0.2f*ar;
    float mn = fmaxf(m, a);
    float sc = expf(m - mn);
    float p  = expf(a - mn);
    s = s*sc + p;
    const float4 vv = *(const float4*)(v + src*256 + co);
    ax = ax*sc + p*vv.x; ay = ay*sc + p*vv.y;
    az = az*sc + p*vv.z; aw = aw*sc + p*vv.w;
    m = mn;
  }
  float inv = 1.f/(s + 1e-16f);
  *(float4*)(out + g*256 + co) = make_float4(ax*inv, ay*inv, az*inv, aw*inv);
}

// ---------- finalize att0 and apply blk2 to the single att0 row ----------
__global__ void att0k(const float* __restrict__ P, const float* __restrict__ S,
                      const float* __restrict__ c20, const float* __restrict__ W1G2,
                      const float* __restrict__ m2w2, const float* __restrict__ m2b2,
                      float* __restrict__ att0b)
{
  __shared__ float a0[256], zs[256], Hs[256];
  __shared__ float part[4];
  __shared__ float stat[2];
  int c = threadIdx.x;
  float av = P[c] / S[c >> 5];
  a0[c] = av;
  float x = av;
  for (int o = 32; o > 0; o >>= 1) x += __shfl_down(x, o);
  if ((c & 63) == 0) part[c >> 6] = x;
  __syncthreads();
  if (c == 0) stat[0] = (part[0]+part[1]+part[2]+part[3])*(1.f/256.f);
  __syncthreads();
  float mu = stat[0];
  float d = av - mu;
  x = d*d;
  for (int o = 32; o > 0; o >>= 1) x += __shfl_down(x, o);
  if ((c & 63) == 0) part[c >> 6] = x;
  __syncthreads();
  if (c == 0) stat[1] = rsqrtf((part[0]+part[1]+part[2]+part[3])*(1.f/256.f) + 1e-5f);
  __syncthreads();
  zs[c] = (av - mu)*stat[1];
  __syncthreads();
  float acc = c20[c];
  for (int k = 0; k < 256; k++) acc = fmaf(zs[k], W1G2[k*256 + c], acc);
  Hs[c] = fmaxf(acc, 0.f);
  __syncthreads();
  float acc2 = m2b2[c];
  for (int k = 0; k < 256; k++) acc2 = fmaf(Hs[k], m2w2[k*256 + c], acc2);
  att0b[c] = a0[c] + acc2;
}

// ---------- launcher ----------
extern "C" void kernel_launch(void* const* d_in, const int* in_sizes, int n_in,
                              void* d_out, int out_size, void* d_ws, size_t ws_size,
                              hipStream_t stream)
{
  const float* x    = (const float*)d_in[0];
  const int*   nidx = (const int*)d_in[1];
  const int*   eidx = (const int*)d_in[2];
  const int*   eord = (const int*)d_in[3];
  const float* pe_q = (const float*)d_in[4];
  const float* qw1  = (const float*)d_in[5];
  const float* qb1  = (const float*)d_in[6];
  const float* qw2  = (const float*)d_in[7];
  const float* qb2  = (const float*)d_in[8];
  const float* kw   = (const float*)d_in[9];
  const float* kb   = (const float*)d_in[10];
  const float* vw   = (const float*)d_in[11];
  const float* vb   = (const float*)d_in[12];
  const float* m1w1 = (const float*)d_in[13];
  const float* m1b1 = (const float*)d_in[14];
  const float* m1w2 = (const float*)d_in[15];
  const float* m1b2 = (const float*)d_in[16];
  const float* m2w1 = (const float*)d_in[17];
  const float* m2b1 = (const float*)d_in[18];
  const float* m2w2 = (const float*)d_in[19];
  const float* m2b2 = (const float*)d_in[20];
  const float* m3w1 = (const float*)d_in[21];
  const float* m3b1 = (const float*)d_in[22];
  const float* m3w2 = (const float*)d_in[23];
  const float* m3b2 = (const float*)d_in[24];
  const float* ln1g = (const float*)d_in[25];
  const float* ln1b = (const float*)d_in[26];
  const float* ln2g = (const float*)d_in[27];
  const float* ln2b = (const float*)d_in[28];
  const float* ln3g = (const float*)d_in[29];
  const float* ln3b = (const float*)d_in[30];
  const float* pe2  = (const float*)d_in[31];
  const float* pe3  = (const float*)d_in[32];
  const float* pe_b = (const float*)d_in[33];
  const float* bw1  = (const float*)d_in[34];
  const float* bb1  = (const float*)d_in[35];
  const float* bw2  = (const float*)d_in[36];
  const float* bb2  = (const float*)d_in[37];

  float* out_v = (float*)d_out;                       // [N,256] (also x1 scratch)
  float* out_e = out_v + (size_t)N_NODES*256;         // [E,256] (also raw att1_e)

  float* ws = (float*)d_ws;
  size_t o = 0;
  float* v     = ws + o; o += (size_t)N_NODES*256;
  float* lb    = ws + o; o += (size_t)N_NODES*16;     // [N,16]: cols 0-7 logit0, 8-15 alpha_r
  float* W1G1  = ws + o; o += 65536;
  float* W1G2  = ws + o; o += 65536;
  float* W1G3  = ws + o; o += 65536;
  float* kwq   = ws + o; o += 4096;
  float* kqb   = ws + o; o += 256;
  float* biasT = ws + o; o += 11*256;
  float* u11   = ws + o; o += 256;
  float* u12   = ws + o; o += 256;
  float* u13   = ws + o; o += 256;
  float* c1v   = ws + o; o += 256;
  float* c2v   = ws + o; o += 256;
  float* c20v  = ws + o; o += 256;
  float* c3tab = ws + o; o += 11*256;
  float* att0b = ws + o; o += 256;
  float* Pacc  = ws + o; o += 256;
  float* Sacc  = ws + o; o += 256;
  unsigned* Mkey = (unsigned*)(ws + o); o += 256;
  int* cnt  = (int*)(ws + o); o += N_EDGES;
  int* offA = (int*)(ws + o); o += N_EDGES;
  int* curA = (int*)(ws + o); o += N_EDGES;
  int* ent  = (int*)(ws + o); o += N_NNZ;
  short* Wpall = (short*)(ws + o); o += 7*32768;      // 7 matrices, bf16 [n][k]
  (void)in_sizes; (void)n_in; (void)out_size; (void)ws_size;

  short* Wp_w1g1 = Wpall + 0*65536;
  short* Wp_w1g2 = Wpall + 1*65536;
  short* Wp_w1g3 = Wpall + 2*65536;
  short* Wp_m1w2 = Wpall + 3*65536;
  short* Wp_m2w2 = Wpall + 4*65536;
  short* Wp_m3w2 = Wpall + 5*65536;
  short* Wp_vw   = Wpall + 6*65536;

  const int GN = (N_NODES + 63)/64;   // 1563
  const int GE = (N_EDGES + 63)/64;   // 782

  prepk<<<17, 256, 0, stream>>>(ln1g, ln1b, m1w1, m1b1, ln2g, ln2b, m2w1, m2b1,
                                ln3g, ln3b, m3w1, m3b1, pe2, pe3,
                                pe_q, qw1, qb1, qw2, qb2, kw, kb,
                                pe_b, bw1, bb1, bw2, bb2,
                                W1G1, W1G2, W1G3, u11, u12, u13,
                                c1v, c2v, c20v, c3tab, kwq, kqb, biasT);
  packk<<<dim3(8, 7), 256, 0, stream>>>(W1G1, W1G2, W1G3, m1w2, m2w2, m3w2, vw, Wpall);
  initk<<<196, 256, 0, stream>>>(cnt, Pacc, Sacc, Mkey);
  countk<<<(N_NNZ + 255)/256, 256, 0, stream>>>(nidx, cnt);

  // x1 = x + MLP1(LN1(x))   -> out_v region
  mlpk<<<GN, 256, 0, stream>>>(x, out_v, N_NODES, Wp_w1g1, u11, c1v, nullptr,
                               Wp_m1w2, m1b2, nullptr, nullptr);
  // v = x1@vw + vb
  gemmk<<<GN, 256, 0, stream>>>(out_v, v, N_NODES, Wp_vw, vb);
  // logits [N,16] = x1@kwq + kqb
  logitk<<<N_NODES/16, 256, 0, stream>>>(out_v, kwq, kqb, lb);

  maxk<<<256, 256, 0, stream>>>(lb, Mkey);
  sumk<<<1024, 256, 0, stream>>>(lb, v, Mkey, Pacc, Sacc);

  scank<<<1, 1024, 0, stream>>>(cnt, offA, curA);
  fillk<<<(N_NNZ + 255)/256, 256, 0, stream>>>(nidx, curA, ent);
  aggk<<<N_EDGES/4, 256, 0, stream>>>(offA, cnt, ent, eidx, lb, v, out_e);

  att0k<<<1, 256, 0, stream>>>(Pacc, Sacc, c20v, W1G2, m2w2, m2b2, att0b);

  // node path: blk2 (+att0b) then blk3 (+bias[1])
  mlpk<<<GN, 256, 0, stream>>>(v, out_v, N_NODES, Wp_w1g2, u12, c2v, nullptr,
                               Wp_m2w2, m2b2, att0b, nullptr);
  mlpk<<<GN, 256, 0, stream>>>(out_v, out_v, N_NODES, Wp_w1g3, u13, c3tab + 256, nullptr,
                               Wp_m3w2, m3b2, biasT + 256, nullptr);
  // edge path: blk2 (+att0b) then blk3 with per-order c3/bias
  mlpk<<<GE, 256, 0, stream>>>(out_e, out_e, N_EDGES, Wp_w1g2, u12, c2v, nullptr,
                               Wp_m2w2, m2b2, att0b, nullptr);
  mlpk<<<GE, 256, 0, stream>>>(out_e, out_e, N_EDGES, Wp_w1g3, u13, c3tab, eord,
                               Wp_m3w2, m3b2, biasT, eord);
}

// Round 5
// 1230.843 us; speedup vs baseline: 2.3634x; 1.2285x over previous
//
#include <hip/hip_runtime.h>
#include <math.h>

#define N_NODES 100000
#define N_EDGES 50000
#define N_NNZ   600000

typedef __attribute__((ext_vector_type(8))) short bf16x8;
typedef __attribute__((ext_vector_type(4))) short bf16x4;
typedef __attribute__((ext_vector_type(4))) float f32x4;

// ---------- helpers ----------
__device__ __forceinline__ unsigned fkey(float f){
  unsigned u = __float_as_uint(f);
  return (u & 0x80000000u) ? ~u : (u | 0x80000000u);
}
__device__ __forceinline__ float fdec(unsigned k){
  return (k & 0x80000000u) ? __uint_as_float(k ^ 0x80000000u) : __uint_as_float(~k);
}
__device__ __forceinline__ short f2bf(float f){
  unsigned u = __float_as_uint(f);
  unsigned r = u + 0x7FFFu + ((u >> 16) & 1u);   // RNE
  return (short)(r >> 16);
}
__device__ __forceinline__ float bf2f(short s){
  return __uint_as_float(((unsigned)(unsigned short)s) << 16);
}

// ---------- prep: weight folds, q/kwq, bias table, constant vectors ----------
__global__ void prepk(
  const float* __restrict__ ln1g, const float* __restrict__ ln1b,
  const float* __restrict__ m1w1, const float* __restrict__ m1b1,
  const float* __restrict__ ln2g, const float* __restrict__ ln2b,
  const float* __restrict__ m2w1, const float* __restrict__ m2b1,
  const float* __restrict__ ln3g, const float* __restrict__ ln3b,
  const float* __restrict__ m3w1, const float* __restrict__ m3b1,
  const float* __restrict__ pe2, const float* __restrict__ pe3,
  const float* __restrict__ pe_q, const float* __restrict__ qw1,
  const float* __restrict__ qb1, const float* __restrict__ qw2,
  const float* __restrict__ qb2, const float* __restrict__ kw,
  const float* __restrict__ kb,
  const float* __restrict__ pe_b, const float* __restrict__ bw1,
  const float* __restrict__ bb1, const float* __restrict__ bw2,
  const float* __restrict__ bb2,
  float* __restrict__ W1G1, float* __restrict__ W1G2, float* __restrict__ W1G3,
  float* __restrict__ u11, float* __restrict__ u12, float* __restrict__ u13,
  float* __restrict__ c1v, float* __restrict__ c2v, float* __restrict__ c20v,
  float* __restrict__ c3tab, float* __restrict__ kwq, float* __restrict__ kqb,
  float* __restrict__ biasT)
{
  const int b = blockIdx.x, tid = threadIdx.x;
  __shared__ float ps[11*256];
  if (b < 4) {
    for (int i = tid; i < 16384; i += 256) { int idx = b*16384 + i; W1G1[idx] = ln1g[idx>>8]*m1w1[idx]; }
  } else if (b < 8) {
    int bb = b-4;
    for (int i = tid; i < 16384; i += 256) { int idx = bb*16384 + i; W1G2[idx] = ln2g[idx>>8]*m2w1[idx]; }
  } else if (b < 12) {
    int bb = b-8;
    for (int i = tid; i < 16384; i += 256) { int idx = bb*16384 + i; W1G3[idx] = ln3g[idx>>8]*m3w1[idx]; }
  } else if (b == 12) {
    int c = tid; float su = 0.f, sc = 0.f;
    for (int k = 0; k < 256; k++) { float w = m1w1[k*256+c]; su += ln1g[k]*w; sc += ln1b[k]*w; }
    u11[c] = su; c1v[c] = m1b1[c] + sc;
  } else if (b == 13) {
    int c = tid; float su = 0.f, sl = 0.f, p0 = 0.f, p1 = 0.f;
    for (int k = 0; k < 256; k++) {
      float wl = m2w1[k*256+c], wh = m2w1[(256+k)*256+c];
      su += ln2g[k]*wl; sl += ln2b[k]*wl; p0 += pe2[k]*wh; p1 += pe2[256+k]*wh;
    }
    u12[c] = su; c2v[c] = m2b1[c] + sl + p1; c20v[c] = m2b1[c] + sl + p0;
  } else if (b == 14) {
    int c = tid; float su = 0.f, sl = 0.f;
    for (int k = 0; k < 256; k++) { float wl = m3w1[k*256+c]; su += ln3g[k]*wl; sl += ln3b[k]*wl; }
    u13[c] = su;
    float base3 = m3b1[c] + sl;
    for (int o = 0; o < 11; o++) {
      float acc = 0.f;
      for (int k = 0; k < 256; k++) acc += pe3[o*256+k]*m3w1[(256+k)*256+c];
      c3tab[o*256+c] = base3 + acc;
    }
  } else if (b == 15) {
    int j = tid;
    for (int r = 0; r < 2; r++) {
      float acc = qb1[j];
      for (int k = 0; k < 64; k++) acc += pe_q[r*64+k]*qw1[k*256+j];
      ps[r*256+j] = fmaxf(acc, 0.f);
    }
    __syncthreads();
    for (int r = 0; r < 2; r++) {
      float acc = qb2[j];
      for (int k = 0; k < 256; k++) acc += ps[r*256+k]*qw2[k*256+j];
      ps[512 + r*256 + j] = acc;
    }
    __syncthreads();
    {
      const float* q0 = &ps[512]; const float* q1 = &ps[768];
      int k = tid;
      for (int h = 0; h < 8; h++) {
        float s0 = 0.f, s1 = 0.f;
        for (int d = 0; d < 32; d++) {
          s0 += kw[k*512 + h*32 + d]       * q0[h*32+d];
          s1 += kw[k*512 + 256 + h*32 + d] * q1[h*32+d];
        }
        kwq[k*16+h]   = s0 * 0.17677669529663687f;  // 1/sqrt(32)
        kwq[k*16+8+h] = s1;
      }
      if (tid < 8) {
        float s0 = 0.f, s1 = 0.f;
        for (int d = 0; d < 32; d++) {
          s0 += kb[tid*32+d]     * q0[tid*32+d];
          s1 += kb[256+tid*32+d] * q1[tid*32+d];
        }
        kqb[tid]   = s0 * 0.17677669529663687f;
        kqb[8+tid] = s1;
      }
    }
  } else if (b == 16) {
    int j = tid;
    for (int o = 0; o < 11; o++) {
      float acc = bb1[j];
      for (int k = 0; k < 64; k++) acc += pe_b[o*64+k]*bw1[k*256+j];
      ps[o*256+j] = fmaxf(acc, 0.f);
    }
    __syncthreads();
    int c = tid;
    for (int o = 0; o < 11; o++) {
      float acc = bb2[c];
      for (int k = 0; k < 256; k++) acc += ps[o*256+k]*bw2[k*256+c];
      biasT[o*256+c] = acc;
    }
  }
}

// ---------- pack fp32 [k][n] -> bf16 [n][k]; y==7 packs kwq [256][16] -> [16][256] ----------
__global__ void packk(const float* __restrict__ s0, const float* __restrict__ s1,
                      const float* __restrict__ s2, const float* __restrict__ s3,
                      const float* __restrict__ s4, const float* __restrict__ s5,
                      const float* __restrict__ s6, short* __restrict__ dst,
                      const float* __restrict__ kwq, short* __restrict__ Kqp)
{
  if (blockIdx.y == 7) {
    int k0 = blockIdx.x*32;
    int j = threadIdx.x & 15, kk = k0 + (threadIdx.x >> 4)*2;
    Kqp[j*256 + kk]   = f2bf(kwq[kk*16 + j]);
    Kqp[j*256 + kk+1] = f2bf(kwq[(kk+1)*16 + j]);
    return;
  }
  const float* srcs[7] = {s0,s1,s2,s3,s4,s5,s6};
  const float* S = srcs[blockIdx.y];
  short* D = dst + (size_t)blockIdx.y*65536;
  int n = threadIdx.x;
  int k0 = blockIdx.x*32;
  short vb[32];
  #pragma unroll
  for (int i = 0; i < 32; i++) vb[i] = f2bf(S[(k0+i)*256 + n]);
  #pragma unroll
  for (int i = 0; i < 4; i++) *(bf16x8*)&D[n*256 + k0 + i*8] = *(bf16x8*)&vb[i*8];
}

// ---------- init scratch ----------
__global__ void initk(int* __restrict__ cnt, float* __restrict__ P,
                      float* __restrict__ S, unsigned* __restrict__ Mkey){
  int i = blockIdx.x*256 + threadIdx.x;
  if (i < N_EDGES) cnt[i] = 0;
  if (i < 256) P[i] = 0.f;
  if (i < 8) { S[i] = 0.f; Mkey[i] = 0u; }
}

// ---------- CSR build ----------
__global__ void countk(const int* __restrict__ nidx, int* __restrict__ cnt){
  int e = blockIdx.x*256 + threadIdx.x;
  if (e < N_NNZ) { int g = nidx[e]; if (g < N_EDGES) atomicAdd(&cnt[g], 1); }
}
__global__ void scank(const int* __restrict__ cnt, int* __restrict__ offA, int* __restrict__ curA){
  __shared__ int sh[1024];
  int tid = threadIdx.x;
  const int PER = (N_EDGES + 1023)/1024;
  int base = tid*PER;
  int s = 0;
  for (int i = 0; i < PER; i++) { int idx = base+i; if (idx < N_EDGES) s += cnt[idx]; }
  sh[tid] = s;
  __syncthreads();
  for (int d = 1; d < 1024; d <<= 1) {
    int v = (tid >= d) ? sh[tid-d] : 0;
    __syncthreads();
    sh[tid] += v;
    __syncthreads();
  }
  int run = (tid == 0) ? 0 : sh[tid-1];
  for (int i = 0; i < PER; i++) {
    int idx = base+i;
    if (idx < N_EDGES) { offA[idx] = run; curA[idx] = run; run += cnt[idx]; }
  }
}
__global__ void fillk(const int* __restrict__ nidx, int* __restrict__ curA, int* __restrict__ ent){
  int e = blockIdx.x*256 + threadIdx.x;
  if (e < N_NNZ) {
    int g = nidx[e];
    if (g < N_EDGES) { int p = atomicAdd(&curA[g], 1); ent[p] = e; }
  }
}

// ---------- shared GEMM helpers ----------
__device__ __forceinline__ void gemm_step(const char* tb, const short* __restrict__ Wp,
    int lr, int lk, int wv, f32x4 acc[4][4])
{
  const int swzA = (lr & 7) << 4;
  const short* wb[4];
  #pragma unroll
  for (int ct = 0; ct < 4; ct++) wb[ct] = Wp + (wv*64 + ct*16 + lr)*256 + lk;
  #pragma unroll
  for (int ks = 0; ks < 8; ks++) {
    bf16x8 a[4], b[4];
    #pragma unroll
    for (int rt = 0; rt < 4; rt++)
      a[rt] = *(const bf16x8*)(tb + (((rt*16 + lr)*512 + ks*64 + lk*2) ^ swzA));
    #pragma unroll
    for (int ct = 0; ct < 4; ct++)
      b[ct] = *(const bf16x8*)(wb[ct] + ks*32);
    #pragma unroll
    for (int rt = 0; rt < 4; rt++)
      #pragma unroll
      for (int ct = 0; ct < 4; ct++)
        acc[rt][ct] = __builtin_amdgcn_mfma_f32_16x16x32_bf16(a[rt], b[ct], acc[rt][ct], 0, 0, 0);
  }
}

__device__ __forceinline__ void stats64(const char* tb, float2* red, float2* rowstat, int tid)
{
  int row = tid >> 2, q = tid & 3;
  int swz = (row & 7) << 4;
  float s = 0.f, s2 = 0.f;
  #pragma unroll
  for (int j = 0; j < 8; j++) {
    bf16x8 h = *(const bf16x8*)(tb + ((row*512 + (q*64 + j*8)*2) ^ swz));
    #pragma unroll
    for (int e = 0; e < 8; e++) { float f = bf2f(h[e]); s += f; s2 += f*f; }
  }
  red[tid] = make_float2(s, s2);
  __syncthreads();
  if (tid < 64) {
    float2 A = red[tid*4+0], B = red[tid*4+1], C = red[tid*4+2], D = red[tid*4+3];
    float ss = A.x+B.x+C.x+D.x, ss2 = A.y+B.y+C.y+D.y;
    float mu = ss * (1.f/256.f);
    float var = fmaxf(ss2*(1.f/256.f) - mu*mu, 0.f);
    rowstat[tid] = make_float2(mu, rsqrtf(var + 1e-5f));
  }
  __syncthreads();
}

__device__ __forceinline__ void epiH(char* outb, const f32x4 acc[4][4],
    const float2* rowstat, const float* __restrict__ u, const float* __restrict__ cvec,
    const int* __restrict__ cidx, int row0, int nrows, int lr, int wv, int rb)
{
  float uv[4];
  #pragma unroll
  for (int ct = 0; ct < 4; ct++) uv[ct] = u[wv*64 + ct*16 + lr];
  #pragma unroll
  for (int rt = 0; rt < 4; rt++) {
    #pragma unroll
    for (int r = 0; r < 4; r++) {
      int rl = rt*16 + rb + r;
      float2 st = rowstat[rl];
      const float* cb = cvec;
      if (cidx != nullptr) {
        int gr = row0 + rl;
        cb = cvec + (size_t)((gr < nrows) ? cidx[gr] : 0)*256;
      }
      int swz = (rl & 7) << 4;
      #pragma unroll
      for (int ct = 0; ct < 4; ct++) {
        int j = wv*64 + ct*16 + lr;
        float h = fmaxf(st.y*(acc[rt][ct][r] - st.x*uv[ct]) + cb[j], 0.f);
        *(short*)(outb + ((rl*512 + j*2) ^ swz)) = f2bf(h);
      }
    }
  }
}

// ---------- fused A: x -> x1 -> {v bf16, logits f32}  (MLP1 + v-proj + logit GEMM) ----------
__global__ __launch_bounds__(256, 2) void fusedAk(
  const float* __restrict__ x,
  const short* __restrict__ Wp1, const float* __restrict__ u1, const float* __restrict__ c1,
  const short* __restrict__ Wp2, const float* __restrict__ b2,
  const short* __restrict__ Wpv, const float* __restrict__ vb,
  const short* __restrict__ Kqp, const float* __restrict__ kqb,
  short* __restrict__ vout, float* __restrict__ lb, int nrows)
{
  __shared__ __align__(16) short bufA[64*256];
  __shared__ __align__(16) short bufB[64*256];
  __shared__ float2 red[256];
  __shared__ float2 rowstat[64];
  char* tA = (char*)bufA; char* tB = (char*)bufB;
  const int tid = threadIdx.x;
  const int wv = tid >> 6, lane = tid & 63;
  const int lr = lane & 15, lk = (lane >> 4)*8, rb = (lane >> 4)*4;
  const int row0 = blockIdx.x * 64;

  { // stage x f32 -> bf16 LDS (swizzled)
    int row = tid >> 2, c0 = (tid & 3)*64;
    bool ok = (row0 + row < nrows);
    const float* sp = x + (size_t)(row0+row)*256 + c0;
    int swz = (row & 7) << 4;
    #pragma unroll
    for (int j = 0; j < 8; j++) {
      float4 f0 = ok ? *(const float4*)(sp + j*8)     : make_float4(0,0,0,0);
      float4 f1 = ok ? *(const float4*)(sp + j*8 + 4) : make_float4(0,0,0,0);
      bf16x8 h;
      h[0]=f2bf(f0.x); h[1]=f2bf(f0.y); h[2]=f2bf(f0.z); h[3]=f2bf(f0.w);
      h[4]=f2bf(f1.x); h[5]=f2bf(f1.y); h[6]=f2bf(f1.z); h[7]=f2bf(f1.w);
      *(bf16x8*)(tA + ((row*512 + (c0+j*8)*2) ^ swz)) = h;
    }
  }
  __syncthreads();
  stats64(tA, red, rowstat, tid);

  const f32x4 zero = {0.f,0.f,0.f,0.f};
  f32x4 acc[4][4];
  #pragma unroll
  for (int rt = 0; rt < 4; rt++)
    #pragma unroll
    for (int ct = 0; ct < 4; ct++) acc[rt][ct] = zero;
  gemm_step(tA, Wp1, lr, lk, wv, acc);
  epiH(tB, acc, rowstat, u1, c1, nullptr, row0, nrows, lr, wv, rb);
  __syncthreads();

  #pragma unroll
  for (int rt = 0; rt < 4; rt++)
    #pragma unroll
    for (int ct = 0; ct < 4; ct++) acc[rt][ct] = zero;
  gemm_step(tB, Wp2, lr, lk, wv, acc);
  { // epi2: x1 = x(f32) + acc + b2 -> bf16 bufA (thread-owned positions)
    float bv[4];
    #pragma unroll
    for (int ct = 0; ct < 4; ct++) bv[ct] = b2[wv*64 + ct*16 + lr];
    #pragma unroll
    for (int rt = 0; rt < 4; rt++) {
      #pragma unroll
      for (int r = 0; r < 4; r++) {
        int rl = rt*16 + rb + r;
        int gr = row0 + rl;
        bool ok = gr < nrows;
        const float* xp = x + (size_t)gr*256;
        int swz = (rl & 7) << 4;
        #pragma unroll
        for (int ct = 0; ct < 4; ct++) {
          int j = wv*64 + ct*16 + lr;
          float xv = ok ? xp[j] : 0.f;
          float x1 = xv + acc[rt][ct][r] + bv[ct];
          *(short*)(tA + ((rl*512 + j*2) ^ swz)) = f2bf(x1);
        }
      }
    }
  }
  __syncthreads();

  #pragma unroll
  for (int rt = 0; rt < 4; rt++)
    #pragma unroll
    for (int ct = 0; ct < 4; ct++) acc[rt][ct] = zero;
  gemm_step(tA, Wpv, lr, lk, wv, acc);
  { // epi3: v = acc + vb -> bf16 global
    float bv[4];
    #pragma unroll
    for (int ct = 0; ct < 4; ct++) bv[ct] = vb[wv*64 + ct*16 + lr];
    #pragma unroll
    for (int rt = 0; rt < 4; rt++) {
      #pragma unroll
      for (int r = 0; r < 4; r++) {
        int rl = rt*16 + rb + r;
        int gr = row0 + rl;
        if (gr >= nrows) continue;
        #pragma unroll
        for (int ct = 0; ct < 4; ct++) {
          int j = wv*64 + ct*16 + lr;
          vout[(size_t)gr*256 + j] = f2bf(acc[rt][ct][r] + bv[ct]);
        }
      }
    }
  }
  { // GEMM4: logits [64,16] = x1 @ Kqp^T + kqb  (each wave: rows wv*16..+15)
    f32x4 aq = zero;
    int arow = wv*16 + lr;
    int swzq = (lr & 7) << 4;
    #pragma unroll
    for (int ks = 0; ks < 8; ks++) {
      bf16x8 a = *(const bf16x8*)(tA + ((arow*512 + ks*64 + lk*2) ^ swzq));
      bf16x8 b = *(const bf16x8*)(Kqp + lr*256 + ks*32 + lk);
      aq = __builtin_amdgcn_mfma_f32_16x16x32_bf16(a, b, aq, 0, 0, 0);
    }
    float kq = kqb[lr];
    #pragma unroll
    for (int r = 0; r < 4; r++) {
      int gr = row0 + wv*16 + rb + r;
      if (gr < nrows) lb[gr*16 + lr] = aq[r] + kq;
    }
  }
}

// ---------- fused blk2+blk3 (node & edge paths) ----------
__global__ __launch_bounds__(256, 2) void fused2k(
  const short* __restrict__ srcb, float* __restrict__ dst, int nrows,
  const short* __restrict__ Wp21, const float* __restrict__ u2, const float* __restrict__ c2,
  const short* __restrict__ Wp22, const float* __restrict__ b22, const float* __restrict__ add2,
  const short* __restrict__ Wp31, const float* __restrict__ u3, const float* __restrict__ c3, const int* __restrict__ c3idx,
  const short* __restrict__ Wp32, const float* __restrict__ b32, const float* __restrict__ add3, const int* __restrict__ a3idx)
{
  __shared__ __align__(16) short bufA[64*256];
  __shared__ __align__(16) short bufB[64*256];
  __shared__ float2 red[256];
  __shared__ float2 rowstat[64];
  char* tA = (char*)bufA; char* tB = (char*)bufB;
  const int tid = threadIdx.x;
  const int wv = tid >> 6, lane = tid & 63;
  const int lr = lane & 15, lk = (lane >> 4)*8, rb = (lane >> 4)*4;
  const int row0 = blockIdx.x * 64;

  { // stage src bf16 -> LDS (swizzled)
    int row = tid >> 2, c0 = (tid & 3)*64;
    bool ok = (row0 + row < nrows);
    const short* sp = srcb + (size_t)(row0+row)*256 + c0;
    int swz = (row & 7) << 4;
    const bf16x8 zz = {0,0,0,0,0,0,0,0};
    #pragma unroll
    for (int j = 0; j < 8; j++) {
      bf16x8 h = ok ? *(const bf16x8*)(sp + j*8) : zz;
      *(bf16x8*)(tA + ((row*512 + (c0+j*8)*2) ^ swz)) = h;
    }
  }
  __syncthreads();
  stats64(tA, red, rowstat, tid);

  const f32x4 zero = {0.f,0.f,0.f,0.f};
  f32x4 acc[4][4];
  #pragma unroll
  for (int rt = 0; rt < 4; rt++)
    #pragma unroll
    for (int ct = 0; ct < 4; ct++) acc[rt][ct] = zero;
  gemm_step(tA, Wp21, lr, lk, wv, acc);
  epiH(tB, acc, rowstat, u2, c2, nullptr, row0, nrows, lr, wv, rb);
  __syncthreads();

  #pragma unroll
  for (int rt = 0; rt < 4; rt++)
    #pragma unroll
    for (int ct = 0; ct < 4; ct++) acc[rt][ct] = zero;
  gemm_step(tB, Wp22, lr, lk, wv, acc);

  float t2r[4][4][4];
  { // epi2: t2 = v(LDS) + acc + b22 + add2 ; keep f32 in regs, bf16 -> bufA
    float bv[4], av[4];
    #pragma unroll
    for (int ct = 0; ct < 4; ct++) {
      int j = wv*64 + ct*16 + lr;
      bv[ct] = b22[j]; av[ct] = add2[j];
    }
    #pragma unroll
    for (int rt = 0; rt < 4; rt++) {
      #pragma unroll
      for (int r = 0; r < 4; r++) {
        int rl = rt*16 + rb + r;
        int swz = (rl & 7) << 4;
        #pragma unroll
        for (int ct = 0; ct < 4; ct++) {
          int j = wv*64 + ct*16 + lr;
          float vres = bf2f(*(const short*)(tA + ((rl*512 + j*2) ^ swz)));
          float t2 = vres + acc[rt][ct][r] + bv[ct] + av[ct];
          t2r[rt][ct][r] = t2;
          *(short*)(tA + ((rl*512 + j*2) ^ swz)) = f2bf(t2);
        }
      }
    }
  }
  __syncthreads();
  stats64(tA, red, rowstat, tid);

  #pragma unroll
  for (int rt = 0; rt < 4; rt++)
    #pragma unroll
    for (int ct = 0; ct < 4; ct++) acc[rt][ct] = zero;
  gemm_step(tA, Wp31, lr, lk, wv, acc);
  epiH(tB, acc, rowstat, u3, c3, c3idx, row0, nrows, lr, wv, rb);
  __syncthreads();

  #pragma unroll
  for (int rt = 0; rt < 4; rt++)
    #pragma unroll
    for (int ct = 0; ct < 4; ct++) acc[rt][ct] = zero;
  gemm_step(tB, Wp32, lr, lk, wv, acc);

  { // epi4: out = t2 + acc + b32 + add3[row] -> f32 global
    float bv[4];
    #pragma unroll
    for (int ct = 0; ct < 4; ct++) bv[ct] = b32[wv*64 + ct*16 + lr];
    #pragma unroll
    for (int rt = 0; rt < 4; rt++) {
      #pragma unroll
      for (int r = 0; r < 4; r++) {
        int rl = rt*16 + rb + r;
        int gr = row0 + rl;
        if (gr >= nrows) continue;
        const float* ap = add3 + (size_t)((a3idx != nullptr) ? a3idx[gr] : 0)*256;
        #pragma unroll
        for (int ct = 0; ct < 4; ct++) {
          int j = wv*64 + ct*16 + lr;
          dst[(size_t)gr*256 + j] = t2r[rt][ct][r] + acc[rt][ct][r] + bv[ct] + ap[j];
        }
      }
    }
  }
}

// ---------- global softmax max over N (per head) ----------
__global__ void maxk(const float* __restrict__ lb, unsigned* __restrict__ Mkey){
  float mx[8];
  #pragma unroll
  for (int h = 0; h < 8; h++) mx[h] = -INFINITY;
  for (int n = blockIdx.x*256 + threadIdx.x; n < N_NODES; n += 65536) {
    float4 a = *(const float4*)&lb[n*16];
    float4 b = *(const float4*)&lb[n*16+4];
    mx[0] = fmaxf(mx[0], a.x); mx[1] = fmaxf(mx[1], a.y);
    mx[2] = fmaxf(mx[2], a.z); mx[3] = fmaxf(mx[3], a.w);
    mx[4] = fmaxf(mx[4], b.x); mx[5] = fmaxf(mx[5], b.y);
    mx[6] = fmaxf(mx[6], b.z); mx[7] = fmaxf(mx[7], b.w);
  }
  __shared__ unsigned bm[8];
  if (threadIdx.x < 8) bm[threadIdx.x] = 0u;
  __syncthreads();
  #pragma unroll
  for (int h = 0; h < 8; h++) atomicMax(&bm[h], fkey(mx[h]));
  __syncthreads();
  if (threadIdx.x < 8) atomicMax(&Mkey[threadIdx.x], bm[threadIdx.x]);
}

// ---------- att0 numerator/denominator partials (v in bf16) ----------
__global__ void sumk(const float* __restrict__ lb, const short* __restrict__ v,
                     const unsigned* __restrict__ Mkey,
                     float* __restrict__ P, float* __restrict__ S)
{
  int tid = threadIdx.x; int h = tid >> 5;
  float Mh = fdec(Mkey[h]);
  float pa = 0.f, sa = 0.f;
  for (int n = blockIdx.x; n < N_NODES; n += gridDim.x) {
    float w = expf(lb[n*16 + h] - Mh);
    pa = fmaf(w, bf2f(v[(size_t)n*256 + tid]), pa);
    sa += w;
  }
  atomicAdd(&P[tid], pa);
  if ((tid & 31) == 0) atomicAdd(&S[h], sa);
}

// ---------- PMA segment softmax + weighted V aggregation (wave per segment, bf16 v) ----------
__global__ __launch_bounds__(256) void aggk(
  const int* __restrict__ offA, const int* __restrict__ cnt,
  const int* __restrict__ ent, const int* __restrict__ eidx,
  const float* __restrict__ lb, const short* __restrict__ v,
  short* __restrict__ out)
{
  int g = blockIdx.x*4 + (threadIdx.x >> 6);
  if (g >= N_EDGES) return;
  int lane = threadIdx.x & 63;
  int h = lane >> 3;
  int co = lane*4;
  int base = offA[g], n = cnt[g];
  float m = -INFINITY, s = 0.f;
  float ax = 0.f, ay = 0.f, az = 0.f, aw = 0.f;
  for (int i = 0; i < n; i++) {
    int src = eidx[ent[base + i]];
    float ar = lb[src*16 + 8 + h];
    float a = (ar > 0.f) ? ar : 0.2f*ar;
    float mn = fmaxf(m, a);
    float sc = expf(m - mn);
    float p  = expf(a - mn);
    s = s*sc + p;
    bf16x4 vv = *(const bf16x4*)(v + (size_t)src*256 + co);
    ax = ax*sc + p*bf2f(vv[0]); ay = ay*sc + p*bf2f(vv[1]);
    az = az*sc + p*bf2f(vv[2]); aw = aw*sc + p*bf2f(vv[3]);
    m = mn;
  }
  float inv = 1.f/(s + 1e-16f);
  bf16x4 o4;
  o4[0] = f2bf(ax*inv); o4[1] = f2bf(ay*inv);
  o4[2] = f2bf(az*inv); o4[3] = f2bf(aw*inv);
  *(bf16x4*)(out + (size_t)g*256 + co) = o4;
}

// ---------- finalize att0 and apply blk2 to the single att0 row ----------
__global__ void att0k(const float* __restrict__ P, const float* __restrict__ S,
                      const float* __restrict__ c20, const float* __restrict__ W1G2,
                      const float* __restrict__ m2w2, const float* __restrict__ m2b2,
                      float* __restrict__ att0b)
{
  __shared__ float a0[256], zs[256], Hs[256];
  __shared__ float part[4];
  __shared__ float stat[2];
  int c = threadIdx.x;
  float av = P[c] / S[c >> 5];
  a0[c] = av;
  float x = av;
  for (int o = 32; o > 0; o >>= 1) x += __shfl_down(x, o);
  if ((c & 63) == 0) part[c >> 6] = x;
  __syncthreads();
  if (c == 0) stat[0] = (part[0]+part[1]+part[2]+part[3])*(1.f/256.f);
  __syncthreads();
  float mu = stat[0];
  float d = av - mu;
  x = d*d;
  for (int o = 32; o > 0; o >>= 1) x += __shfl_down(x, o);
  if ((c & 63) == 0) part[c >> 6] = x;
  __syncthreads();
  if (c == 0) stat[1] = rsqrtf((part[0]+part[1]+part[2]+part[3])*(1.f/256.f) + 1e-5f);
  __syncthreads();
  zs[c] = (av - mu)*stat[1];
  __syncthreads();
  float acc = c20[c];
  for (int k = 0; k < 256; k++) acc = fmaf(zs[k], W1G2[k*256 + c], acc);
  Hs[c] = fmaxf(acc, 0.f);
  __syncthreads();
  float acc2 = m2b2[c];
  for (int k = 0; k < 256; k++) acc2 = fmaf(Hs[k], m2w2[k*256 + c], acc2);
  att0b[c] = a0[c] + acc2;
}

// ---------- launcher ----------
extern "C" void kernel_launch(void* const* d_in, const int* in_sizes, int n_in,
                              void* d_out, int out_size, void* d_ws, size_t ws_size,
                              hipStream_t stream)
{
  const float* x    = (const float*)d_in[0];
  const int*   nidx = (const int*)d_in[1];
  const int*   eidx = (const int*)d_in[2];
  const int*   eord = (const int*)d_in[3];
  const float* pe_q = (const float*)d_in[4];
  const float* qw1  = (const float*)d_in[5];
  const float* qb1  = (const float*)d_in[6];
  const float* qw2  = (const float*)d_in[7];
  const float* qb2  = (const float*)d_in[8];
  const float* kw   = (const float*)d_in[9];
  const float* kb   = (const float*)d_in[10];
  const float* vw   = (const float*)d_in[11];
  const float* vb   = (const float*)d_in[12];
  const float* m1w1 = (const float*)d_in[13];
  const float* m1b1 = (const float*)d_in[14];
  const float* m1w2 = (const float*)d_in[15];
  const float* m1b2 = (const float*)d_in[16];
  const float* m2w1 = (const float*)d_in[17];
  const float* m2b1 = (const float*)d_in[18];
  const float* m2w2 = (const float*)d_in[19];
  const float* m2b2 = (const float*)d_in[20];
  const float* m3w1 = (const float*)d_in[21];
  const float* m3b1 = (const float*)d_in[22];
  const float* m3w2 = (const float*)d_in[23];
  const float* m3b2 = (const float*)d_in[24];
  const float* ln1g = (const float*)d_in[25];
  const float* ln1b = (const float*)d_in[26];
  const float* ln2g = (const float*)d_in[27];
  const float* ln2b = (const float*)d_in[28];
  const float* ln3g = (const float*)d_in[29];
  const float* ln3b = (const float*)d_in[30];
  const float* pe2  = (const float*)d_in[31];
  const float* pe3  = (const float*)d_in[32];
  const float* pe_b = (const float*)d_in[33];
  const float* bw1  = (const float*)d_in[34];
  const float* bb1  = (const float*)d_in[35];
  const float* bw2  = (const float*)d_in[36];
  const float* bb2  = (const float*)d_in[37];

  float* out_v = (float*)d_out;                       // [N,256] f32 final
  float* out_e = out_v + (size_t)N_NODES*256;         // [E,256] f32 final

  float* ws = (float*)d_ws;
  size_t o = 0;
  short* vbf  = (short*)(ws + o); o += (size_t)N_NODES*128;   // v bf16 [N,256]
  short* aeb  = (short*)(ws + o); o += (size_t)N_EDGES*128;   // att1_e bf16 [E,256]
  float* lb    = ws + o; o += (size_t)N_NODES*16;
  float* W1G1  = ws + o; o += 65536;
  float* W1G2  = ws + o; o += 65536;
  float* W1G3  = ws + o; o += 65536;
  float* kwq   = ws + o; o += 4096;
  float* kqb   = ws + o; o += 256;
  float* biasT = ws + o; o += 11*256;
  float* u11   = ws + o; o += 256;
  float* u12   = ws + o; o += 256;
  float* u13   = ws + o; o += 256;
  float* c1v   = ws + o; o += 256;
  float* c2v   = ws + o; o += 256;
  float* c20v  = ws + o; o += 256;
  float* c3tab = ws + o; o += 11*256;
  float* att0b = ws + o; o += 256;
  float* Pacc  = ws + o; o += 256;
  float* Sacc  = ws + o; o += 256;
  unsigned* Mkey = (unsigned*)(ws + o); o += 256;
  int* cnt  = (int*)(ws + o); o += N_EDGES;
  int* offA = (int*)(ws + o); o += N_EDGES;
  int* curA = (int*)(ws + o); o += N_EDGES;
  int* ent  = (int*)(ws + o); o += N_NNZ;
  short* Wpall = (short*)(ws + o); o += 7*32768;      // 7 matrices, bf16 [n][k]
  short* Kqp   = (short*)(ws + o); o += 2048;         // kwq bf16 [16][256]
  (void)in_sizes; (void)n_in; (void)out_size; (void)ws_size;

  short* Wp_w1g1 = Wpall + 0*65536;
  short* Wp_w1g2 = Wpall + 1*65536;
  short* Wp_w1g3 = Wpall + 2*65536;
  short* Wp_m1w2 = Wpall + 3*65536;
  short* Wp_m2w2 = Wpall + 4*65536;
  short* Wp_m3w2 = Wpall + 5*65536;
  short* Wp_vw   = Wpall + 6*65536;

  const int GN = (N_NODES + 63)/64;   // 1563
  const int GE = (N_EDGES + 63)/64;   // 782

  prepk<<<17, 256, 0, stream>>>(ln1g, ln1b, m1w1, m1b1, ln2g, ln2b, m2w1, m2b1,
                                ln3g, ln3b, m3w1, m3b1, pe2, pe3,
                                pe_q, qw1, qb1, qw2, qb2, kw, kb,
                                pe_b, bw1, bb1, bw2, bb2,
                                W1G1, W1G2, W1G3, u11, u12, u13,
                                c1v, c2v, c20v, c3tab, kwq, kqb, biasT);
  packk<<<dim3(8, 8), 256, 0, stream>>>(W1G1, W1G2, W1G3, m1w2, m2w2, m3w2, vw, Wpall, kwq, Kqp);
  initk<<<196, 256, 0, stream>>>(cnt, Pacc, Sacc, Mkey);
  countk<<<(N_NNZ + 255)/256, 256, 0, stream>>>(nidx, cnt);

  // x -> x1 -> {v bf16, logits}
  fusedAk<<<GN, 256, 0, stream>>>(x, Wp_w1g1, u11, c1v, Wp_m1w2, m1b2,
                                  Wp_vw, vb, Kqp, kqb, vbf, lb, N_NODES);

  maxk<<<256, 256, 0, stream>>>(lb, Mkey);
  sumk<<<1024, 256, 0, stream>>>(lb, vbf, Mkey, Pacc, Sacc);

  scank<<<1, 1024, 0, stream>>>(cnt, offA, curA);
  fillk<<<(N_NNZ + 255)/256, 256, 0, stream>>>(nidx, curA, ent);
  aggk<<<N_EDGES/4, 256, 0, stream>>>(offA, cnt, ent, eidx, lb, vbf, aeb);

  att0k<<<1, 256, 0, stream>>>(Pacc, Sacc, c20v, W1G2, m2w2, m2b2, att0b);

  // node path: fused blk2+blk3
  fused2k<<<GN, 256, 0, stream>>>(vbf, out_v, N_NODES,
                                  Wp_w1g2, u12, c2v, Wp_m2w2, m2b2, att0b,
                                  Wp_w1g3, u13, c3tab + 256, nullptr,
                                  Wp_m3w2, m3b2, biasT + 256, nullptr);
  // edge path: fused blk2+blk3 with per-order c3/bias
  fused2k<<<GE, 256, 0, stream>>>(aeb, out_e, N_EDGES,
                                  Wp_w1g2, u12, c2v, Wp_m2w2, m2b2, att0b,
                                  Wp_w1g3, u13, c3tab, eord,
                                  Wp_m3w2, m3b2, biasT, eord);
}

// Round 8
// 1200.019 us; speedup vs baseline: 2.4241x; 1.0257x over previous
//
#include <hip/hip_runtime.h>
#include <math.h>

#define N_NODES 100000
#define N_EDGES 50000
#define N_NNZ   600000

typedef __attribute__((ext_vector_type(8))) short bf16x8;
typedef __attribute__((ext_vector_type(4))) short bf16x4;
typedef __attribute__((ext_vector_type(4))) float f32x4;

// ---------- helpers ----------
__device__ __forceinline__ unsigned fkey(float f){
  unsigned u = __float_as_uint(f);
  return (u & 0x80000000u) ? ~u : (u | 0x80000000u);
}
__device__ __forceinline__ float fdec(unsigned k){
  return (k & 0x80000000u) ? __uint_as_float(k ^ 0x80000000u) : __uint_as_float(~k);
}
__device__ __forceinline__ short f2bf(float f){
  unsigned u = __float_as_uint(f);
  unsigned r = u + 0x7FFFu + ((u >> 16) & 1u);   // RNE
  return (short)(r >> 16);
}
__device__ __forceinline__ float bf2f(short s){
  return __uint_as_float(((unsigned)(unsigned short)s) << 16);
}

// ---------- prep: weight folds, q/kwq, bias table, constant vectors ----------
__global__ void prepk(
  const float* __restrict__ ln1g, const float* __restrict__ ln1b,
  const float* __restrict__ m1w1, const float* __restrict__ m1b1,
  const float* __restrict__ ln2g, const float* __restrict__ ln2b,
  const float* __restrict__ m2w1, const float* __restrict__ m2b1,
  const float* __restrict__ ln3g, const float* __restrict__ ln3b,
  const float* __restrict__ m3w1, const float* __restrict__ m3b1,
  const float* __restrict__ pe2, const float* __restrict__ pe3,
  const float* __restrict__ pe_q, const float* __restrict__ qw1,
  const float* __restrict__ qb1, const float* __restrict__ qw2,
  const float* __restrict__ qb2, const float* __restrict__ kw,
  const float* __restrict__ kb,
  const float* __restrict__ pe_b, const float* __restrict__ bw1,
  const float* __restrict__ bb1, const float* __restrict__ bw2,
  const float* __restrict__ bb2,
  float* __restrict__ W1G1, float* __restrict__ W1G2, float* __restrict__ W1G3,
  float* __restrict__ u11, float* __restrict__ u12, float* __restrict__ u13,
  float* __restrict__ c1v, float* __restrict__ c2v, float* __restrict__ c20v,
  float* __restrict__ c3tab, float* __restrict__ kwq, float* __restrict__ kqb,
  float* __restrict__ biasT)
{
  const int b = blockIdx.x, tid = threadIdx.x;
  __shared__ float ps[11*256];
  if (b < 4) {
    for (int i = tid; i < 16384; i += 256) { int idx = b*16384 + i; W1G1[idx] = ln1g[idx>>8]*m1w1[idx]; }
  } else if (b < 8) {
    int bb = b-4;
    for (int i = tid; i < 16384; i += 256) { int idx = bb*16384 + i; W1G2[idx] = ln2g[idx>>8]*m2w1[idx]; }
  } else if (b < 12) {
    int bb = b-8;
    for (int i = tid; i < 16384; i += 256) { int idx = bb*16384 + i; W1G3[idx] = ln3g[idx>>8]*m3w1[idx]; }
  } else if (b == 12) {
    int c = tid; float su = 0.f, sc = 0.f;
    for (int k = 0; k < 256; k++) { float w = m1w1[k*256+c]; su += ln1g[k]*w; sc += ln1b[k]*w; }
    u11[c] = su; c1v[c] = m1b1[c] + sc;
  } else if (b == 13) {
    int c = tid; float su = 0.f, sl = 0.f, p0 = 0.f, p1 = 0.f;
    for (int k = 0; k < 256; k++) {
      float wl = m2w1[k*256+c], wh = m2w1[(256+k)*256+c];
      su += ln2g[k]*wl; sl += ln2b[k]*wl; p0 += pe2[k]*wh; p1 += pe2[256+k]*wh;
    }
    u12[c] = su; c2v[c] = m2b1[c] + sl + p1; c20v[c] = m2b1[c] + sl + p0;
  } else if (b == 14) {
    int c = tid; float su = 0.f, sl = 0.f;
    for (int k = 0; k < 256; k++) { float wl = m3w1[k*256+c]; su += ln3g[k]*wl; sl += ln3b[k]*wl; }
    u13[c] = su;
    float base3 = m3b1[c] + sl;
    for (int o = 0; o < 11; o++) {
      float acc = 0.f;
      for (int k = 0; k < 256; k++) acc += pe3[o*256+k]*m3w1[(256+k)*256+c];
      c3tab[o*256+c] = base3 + acc;
    }
  } else if (b == 15) {
    int j = tid;
    for (int r = 0; r < 2; r++) {
      float acc = qb1[j];
      for (int k = 0; k < 64; k++) acc += pe_q[r*64+k]*qw1[k*256+j];
      ps[r*256+j] = fmaxf(acc, 0.f);
    }
    __syncthreads();
    for (int r = 0; r < 2; r++) {
      float acc = qb2[j];
      for (int k = 0; k < 256; k++) acc += ps[r*256+k]*qw2[k*256+j];
      ps[512 + r*256 + j] = acc;
    }
    __syncthreads();
    {
      const float* q0 = &ps[512]; const float* q1 = &ps[768];
      int k = tid;
      for (int h = 0; h < 8; h++) {
        float s0 = 0.f, s1 = 0.f;
        for (int d = 0; d < 32; d++) {
          s0 += kw[k*512 + h*32 + d]       * q0[h*32+d];
          s1 += kw[k*512 + 256 + h*32 + d] * q1[h*32+d];
        }
        kwq[k*16+h]   = s0 * 0.17677669529663687f;  // 1/sqrt(32)
        kwq[k*16+8+h] = s1;
      }
      if (tid < 8) {
        float s0 = 0.f, s1 = 0.f;
        for (int d = 0; d < 32; d++) {
          s0 += kb[tid*32+d]     * q0[tid*32+d];
          s1 += kb[256+tid*32+d] * q1[tid*32+d];
        }
        kqb[tid]   = s0 * 0.17677669529663687f;
        kqb[8+tid] = s1;
      }
    }
  } else if (b == 16) {
    int j = tid;
    for (int o = 0; o < 11; o++) {
      float acc = bb1[j];
      for (int k = 0; k < 64; k++) acc += pe_b[o*64+k]*bw1[k*256+j];
      ps[o*256+j] = fmaxf(acc, 0.f);
    }
    __syncthreads();
    int c = tid;
    for (int o = 0; o < 11; o++) {
      float acc = bb2[c];
      for (int k = 0; k < 256; k++) acc += ps[o*256+k]*bw2[k*256+c];
      biasT[o*256+c] = acc;
    }
  }
}

// ---------- pack fp32 [k][n] -> bf16 [n][k]; y==7 packs kwq [256][16] -> [16][256] ----------
__global__ void packk(const float* __restrict__ s0, const float* __restrict__ s1,
                      const float* __restrict__ s2, const float* __restrict__ s3,
                      const float* __restrict__ s4, const float* __restrict__ s5,
                      const float* __restrict__ s6, short* __restrict__ dst,
                      const float* __restrict__ kwq, short* __restrict__ Kqp)
{
  if (blockIdx.y == 7) {
    int k0 = blockIdx.x*32;
    int j = threadIdx.x & 15, kk = k0 + (threadIdx.x >> 4)*2;
    Kqp[j*256 + kk]   = f2bf(kwq[kk*16 + j]);
    Kqp[j*256 + kk+1] = f2bf(kwq[(kk+1)*16 + j]);
    return;
  }
  const float* srcs[7] = {s0,s1,s2,s3,s4,s5,s6};
  const float* S = srcs[blockIdx.y];
  short* D = dst + (size_t)blockIdx.y*65536;
  int n = threadIdx.x;
  int k0 = blockIdx.x*32;
  short vb[32];
  #pragma unroll
  for (int i = 0; i < 32; i++) vb[i] = f2bf(S[(k0+i)*256 + n]);
  #pragma unroll
  for (int i = 0; i < 4; i++) *(bf16x8*)&D[n*256 + k0 + i*8] = *(bf16x8*)&vb[i*8];
}

// ---------- init scratch ----------
__global__ void initk(int* __restrict__ cnt, float* __restrict__ P,
                      float* __restrict__ S, unsigned* __restrict__ Mkey){
  int i = blockIdx.x*256 + threadIdx.x;
  if (i < N_EDGES) cnt[i] = 0;
  if (i < 256) P[i] = 0.f;
  if (i < 8) { S[i] = 0.f; Mkey[i] = 0u; }
}

// ---------- CSR build ----------
__global__ void countk(const int* __restrict__ nidx, int* __restrict__ cnt){
  int e = blockIdx.x*256 + threadIdx.x;
  if (e < N_NNZ) { int g = nidx[e]; if (g < N_EDGES) atomicAdd(&cnt[g], 1); }
}
__global__ void scank(const int* __restrict__ cnt, int* __restrict__ offA, int* __restrict__ curA){
  __shared__ int sh[1024];
  int tid = threadIdx.x;
  const int PER = (N_EDGES + 1023)/1024;
  int base = tid*PER;
  int s = 0;
  for (int i = 0; i < PER; i++) { int idx = base+i; if (idx < N_EDGES) s += cnt[idx]; }
  sh[tid] = s;
  __syncthreads();
  for (int d = 1; d < 1024; d <<= 1) {
    int v = (tid >= d) ? sh[tid-d] : 0;
    __syncthreads();
    sh[tid] += v;
    __syncthreads();
  }
  int run = (tid == 0) ? 0 : sh[tid-1];
  for (int i = 0; i < PER; i++) {
    int idx = base+i;
    if (idx < N_EDGES) { offA[idx] = run; curA[idx] = run; run += cnt[idx]; }
  }
}
__global__ void fillk(const int* __restrict__ nidx, int* __restrict__ curA, int* __restrict__ ent){
  int e = blockIdx.x*256 + threadIdx.x;
  if (e < N_NNZ) {
    int g = nidx[e];
    if (g < N_EDGES) { int p = atomicAdd(&curA[g], 1); ent[p] = e; }
  }
}

// ---------- 512-thread / 8-wave GEMM helpers ----------
// Wave wv owns cols [wv*32, wv*32+32); ct in {0,1}. acc[rt][ct] covers rows rt*16.., cols wv*32+ct*16..
__device__ __forceinline__ void gemm8(const char* tb, const short* __restrict__ Wp,
    int lr, int lk, int wv, f32x4 acc[4][2])
{
  const int swzA = (lr & 7) << 4;
  const short* w0 = Wp + (size_t)(wv*32 + lr)*256 + lk;
  const short* w1 = w0 + 16*256;
  #pragma unroll
  for (int ks = 0; ks < 8; ks++) {
    bf16x8 a[4];
    #pragma unroll
    for (int rt = 0; rt < 4; rt++)
      a[rt] = *(const bf16x8*)(tb + (((rt*16 + lr)*512 + ks*64 + lk*2) ^ swzA));
    bf16x8 b0 = *(const bf16x8*)(w0 + ks*32);
    bf16x8 b1 = *(const bf16x8*)(w1 + ks*32);
    #pragma unroll
    for (int rt = 0; rt < 4; rt++) {
      acc[rt][0] = __builtin_amdgcn_mfma_f32_16x16x32_bf16(a[rt], b0, acc[rt][0], 0, 0, 0);
      acc[rt][1] = __builtin_amdgcn_mfma_f32_16x16x32_bf16(a[rt], b1, acc[rt][1], 0, 0, 0);
    }
  }
}

__device__ __forceinline__ void zacc(f32x4 acc[4][2]){
  const f32x4 z = {0.f,0.f,0.f,0.f};
  #pragma unroll
  for (int rt = 0; rt < 4; rt++) { acc[rt][0] = z; acc[rt][1] = z; }
}

__device__ __forceinline__ void stats512(const char* tb, float2* red, float2* rowstat, int tid)
{
  int row = tid >> 3, q = tid & 7;
  int swz = (row & 7) << 4;
  float s = 0.f, s2 = 0.f;
  #pragma unroll
  for (int j = 0; j < 4; j++) {
    bf16x8 h = *(const bf16x8*)(tb + ((row*512 + (q*32 + j*8)*2) ^ swz));
    #pragma unroll
    for (int e = 0; e < 8; e++) { float f = bf2f(h[e]); s += f; s2 += f*f; }
  }
  red[tid] = make_float2(s, s2);
  __syncthreads();
  if (tid < 64) {
    float ss = 0.f, ss2 = 0.f;
    #pragma unroll
    for (int k = 0; k < 8; k++) { float2 p = red[tid*8+k]; ss += p.x; ss2 += p.y; }
    float mu = ss * (1.f/256.f);
    float var = fmaxf(ss2*(1.f/256.f) - mu*mu, 0.f);
    rowstat[tid] = make_float2(mu, rsqrtf(var + 1e-5f));
  }
  __syncthreads();
}

__device__ __forceinline__ void epiH512(char* outb, const f32x4 acc[4][2],
    const float2* rowstat, const float* __restrict__ u, const float* __restrict__ cvec,
    const int* __restrict__ cidx, int row0, int nrows, int lr, int wv, int rb)
{
  float uv0 = u[wv*32 + lr], uv1 = u[wv*32 + 16 + lr];
  const int j0 = wv*32 + lr, j1 = j0 + 16;
  #pragma unroll
  for (int rt = 0; rt < 4; rt++) {
    #pragma unroll
    for (int r = 0; r < 4; r++) {
      int rl = rt*16 + rb + r;
      float2 st = rowstat[rl];
      const float* cb = cvec;
      if (cidx != nullptr) {
        int gr = row0 + rl;
        cb = cvec + (size_t)((gr < nrows) ? cidx[gr] : 0)*256;
      }
      int swz = (rl & 7) << 4;
      float h0 = fmaxf(st.y*(acc[rt][0][r] - st.x*uv0) + cb[j0], 0.f);
      float h1 = fmaxf(st.y*(acc[rt][1][r] - st.x*uv1) + cb[j1], 0.f);
      *(short*)(outb + ((rl*512 + j0*2) ^ swz)) = f2bf(h0);
      *(short*)(outb + ((rl*512 + j1*2) ^ swz)) = f2bf(h1);
    }
  }
}

// ---------- fused A: x -> x1 -> {v bf16, logits f32} ----------
__global__ __launch_bounds__(512, 4) void fusedAk(
  const float* __restrict__ x,
  const short* __restrict__ Wp1, const float* __restrict__ u1, const float* __restrict__ c1,
  const short* __restrict__ Wp2, const float* __restrict__ b2,
  const short* __restrict__ Wpv, const float* __restrict__ vb,
  const short* __restrict__ Kqp, const float* __restrict__ kqb,
  short* __restrict__ vout, float* __restrict__ lb, int nrows)
{
  __shared__ __align__(16) char smem[65536];
  __shared__ float2 red[512];
  __shared__ float2 rowstat[64];
  char* tA = smem;
  char* tB = smem + 32768;
  const int tid = threadIdx.x;
  const int wv = tid >> 6, lane = tid & 63;
  const int lr = lane & 15, lk = (lane >> 4)*8, rb = (lane >> 4)*4;
  const int row0 = blockIdx.x * 64;
  const int j0 = wv*32 + lr, j1 = j0 + 16;

  { // stage x f32 -> bf16 tA (swizzled)
    int row = tid >> 3, c0 = (tid & 7)*32;
    bool ok = (row0 + row < nrows);
    const float* sp = x + (size_t)(row0+row)*256 + c0;
    int swz = (row & 7) << 4;
    #pragma unroll
    for (int j = 0; j < 4; j++) {
      float4 f0 = ok ? *(const float4*)(sp + j*8)     : make_float4(0,0,0,0);
      float4 f1 = ok ? *(const float4*)(sp + j*8 + 4) : make_float4(0,0,0,0);
      bf16x8 h;
      h[0]=f2bf(f0.x); h[1]=f2bf(f0.y); h[2]=f2bf(f0.z); h[3]=f2bf(f0.w);
      h[4]=f2bf(f1.x); h[5]=f2bf(f1.y); h[6]=f2bf(f1.z); h[7]=f2bf(f1.w);
      *(bf16x8*)(tA + ((row*512 + (c0+j*8)*2) ^ swz)) = h;
    }
  }
  __syncthreads();
  stats512(tA, red, rowstat, tid);

  f32x4 acc[4][2];
  zacc(acc);
  gemm8(tA, Wp1, lr, lk, wv, acc);
  epiH512(tB, acc, rowstat, u1, c1, nullptr, row0, nrows, lr, wv, rb);
  __syncthreads();

  zacc(acc);
  gemm8(tB, Wp2, lr, lk, wv, acc);
  { // epi2: x1 = x(f32, re-read L2-hot) + acc + b2 -> bf16 tA
    float bv0 = b2[j0], bv1 = b2[j1];
    #pragma unroll
    for (int rt = 0; rt < 4; rt++) {
      #pragma unroll
      for (int r = 0; r < 4; r++) {
        int rl = rt*16 + rb + r;
        int gr = row0 + rl;
        bool ok = gr < nrows;
        const float* xp = x + (size_t)gr*256;
        int swz = (rl & 7) << 4;
        float x0 = ok ? xp[j0] : 0.f;
        float x1v = ok ? xp[j1] : 0.f;
        *(short*)(tA + ((rl*512 + j0*2) ^ swz)) = f2bf(x0 + acc[rt][0][r] + bv0);
        *(short*)(tA + ((rl*512 + j1*2) ^ swz)) = f2bf(x1v + acc[rt][1][r] + bv1);
      }
    }
  }
  __syncthreads();

  zacc(acc);
  gemm8(tA, Wpv, lr, lk, wv, acc);

  // logit GEMM on waves 0-3 (rows wv*16..+15)
  f32x4 aq = {0.f,0.f,0.f,0.f};
  if (wv < 4) {
    int arow = wv*16 + lr;
    int swzq = (lr & 7) << 4;
    #pragma unroll
    for (int ks = 0; ks < 8; ks++) {
      bf16x8 a = *(const bf16x8*)(tA + ((arow*512 + ks*64 + lk*2) ^ swzq));
      bf16x8 b = *(const bf16x8*)(Kqp + lr*256 + ks*32 + lk);
      aq = __builtin_amdgcn_mfma_f32_16x16x32_bf16(a, b, aq, 0, 0, 0);
    }
  }

  { // v fragments -> tB (linear bf16 [64][256])
    float vb0 = vb[j0], vb1 = vb[j1];
    short* tv = (short*)tB;
    #pragma unroll
    for (int rt = 0; rt < 4; rt++) {
      #pragma unroll
      for (int r = 0; r < 4; r++) {
        int rl = rt*16 + rb + r;
        tv[rl*256 + j0] = f2bf(acc[rt][0][r] + vb0);
        tv[rl*256 + j1] = f2bf(acc[rt][1][r] + vb1);
      }
    }
  }
  __syncthreads();
  { // coalesced v store
    const short* tv = (const short*)tB;
    #pragma unroll
    for (int i = 0; i < 4; i++) {
      int s = i*512 + tid;
      int row = s >> 5, gr = row0 + row;
      if (gr < nrows)
        *(bf16x8*)&vout[(size_t)gr*256 + (s & 31)*8] = *(const bf16x8*)&tv[(size_t)s*8];
    }
  }
  if (wv < 4) { // lb store
    float kq = kqb[lr];
    #pragma unroll
    for (int r = 0; r < 4; r++) {
      int gr = row0 + wv*16 + rb + r;
      if (gr < nrows) lb[(size_t)gr*16 + lr] = aq[r] + kq;
    }
  }
}

// ---------- fused blk2+blk3 (node & edge paths) ----------
__global__ __launch_bounds__(512, 4) void fused2k(
  const short* __restrict__ srcb, float* __restrict__ dst, int nrows,
  const short* __restrict__ Wp21, const float* __restrict__ u2, const float* __restrict__ c2,
  const short* __restrict__ Wp22, const float* __restrict__ b22, const float* __restrict__ add2,
  const short* __restrict__ Wp31, const float* __restrict__ u3, const float* __restrict__ c3, const int* __restrict__ c3idx,
  const short* __restrict__ Wp32, const float* __restrict__ b32, const float* __restrict__ add3, const int* __restrict__ a3idx)
{
  __shared__ __align__(16) char smem[65536];
  __shared__ float2 red[512];
  __shared__ float2 rowstat[64];
  char* tA = smem;
  char* tB = smem + 32768;
  const int tid = threadIdx.x;
  const int wv = tid >> 6, lane = tid & 63;
  const int lr = lane & 15, lk = (lane >> 4)*8, rb = (lane >> 4)*4;
  const int row0 = blockIdx.x * 64;
  const int j0 = wv*32 + lr, j1 = j0 + 16;

  { // stage src bf16 -> tA (swizzled)
    int row = tid >> 3, c0 = (tid & 7)*32;
    bool ok = (row0 + row < nrows);
    const short* sp = srcb + (size_t)(row0+row)*256 + c0;
    int swz = (row & 7) << 4;
    const bf16x8 zz = {0,0,0,0,0,0,0,0};
    #pragma unroll
    for (int j = 0; j < 4; j++) {
      bf16x8 h = ok ? *(const bf16x8*)(sp + j*8) : zz;
      *(bf16x8*)(tA + ((row*512 + (c0+j*8)*2) ^ swz)) = h;
    }
  }
  __syncthreads();
  stats512(tA, red, rowstat, tid);

  f32x4 acc[4][2];
  zacc(acc);
  gemm8(tA, Wp21, lr, lk, wv, acc);
  epiH512(tB, acc, rowstat, u2, c2, nullptr, row0, nrows, lr, wv, rb);
  __syncthreads();

  zacc(acc);
  gemm8(tB, Wp22, lr, lk, wv, acc);

  f32x4 t2a[4], t2b[4];   // f32 residual, 32 regs total
  { // epi2: t2 = v(tA) + acc + b22 + add2; keep f32, write bf16 -> tA
    float bv0 = b22[j0], bv1 = b22[j1];
    float av0 = add2[j0], av1 = add2[j1];
    #pragma unroll
    for (int rt = 0; rt < 4; rt++) {
      #pragma unroll
      for (int r = 0; r < 4; r++) {
        int rl = rt*16 + rb + r;
        int swz = (rl & 7) << 4;
        float v0 = bf2f(*(const short*)(tA + ((rl*512 + j0*2) ^ swz)));
        float v1 = bf2f(*(const short*)(tA + ((rl*512 + j1*2) ^ swz)));
        float t0 = v0 + acc[rt][0][r] + bv0 + av0;
        float t1 = v1 + acc[rt][1][r] + bv1 + av1;
        t2a[rt][r] = t0; t2b[rt][r] = t1;
        *(short*)(tA + ((rl*512 + j0*2) ^ swz)) = f2bf(t0);
        *(short*)(tA + ((rl*512 + j1*2) ^ swz)) = f2bf(t1);
      }
    }
  }
  __syncthreads();
  stats512(tA, red, rowstat, tid);

  zacc(acc);
  gemm8(tA, Wp31, lr, lk, wv, acc);
  epiH512(tB, acc, rowstat, u3, c3, c3idx, row0, nrows, lr, wv, rb);
  __syncthreads();

  zacc(acc);
  gemm8(tB, Wp32, lr, lk, wv, acc);
  __syncthreads();   // all tB reads done before smemF overwrite

  { // epi4 -> f32 staging in smem (full 64KB), then coalesced store
    float* smemF = (float*)smem;
    float bv0 = b32[j0], bv1 = b32[j1];
    #pragma unroll
    for (int rt = 0; rt < 4; rt++) {
      #pragma unroll
      for (int r = 0; r < 4; r++) {
        int rl = rt*16 + rb + r;
        int gr = row0 + rl;
        int ai = (a3idx != nullptr && gr < nrows) ? a3idx[gr] : 0;
        const float* ap = add3 + (size_t)ai*256;
        smemF[rl*256 + j0] = t2a[rt][r] + acc[rt][0][r] + bv0 + ap[j0];
        smemF[rl*256 + j1] = t2b[rt][r] + acc[rt][1][r] + bv1 + ap[j1];
      }
    }
    __syncthreads();
    #pragma unroll
    for (int i = 0; i < 8; i++) {
      int s = i*512 + tid;
      int row = s >> 6, gr = row0 + row;
      if (gr < nrows)
        *(float4*)&dst[(size_t)gr*256 + (s & 63)*4] = *(const float4*)&smemF[(size_t)s*4];
    }
  }
}

// ---------- global softmax max over N (per head) ----------
__global__ void maxk(const float* __restrict__ lb, unsigned* __restrict__ Mkey){
  float mx[8];
  #pragma unroll
  for (int h = 0; h < 8; h++) mx[h] = -INFINITY;
  for (int n = blockIdx.x*256 + threadIdx.x; n < N_NODES; n += 65536) {
    float4 a = *(const float4*)&lb[n*16];
    float4 b = *(const float4*)&lb[n*16+4];
    mx[0] = fmaxf(mx[0], a.x); mx[1] = fmaxf(mx[1], a.y);
    mx[2] = fmaxf(mx[2], a.z); mx[3] = fmaxf(mx[3], a.w);
    mx[4] = fmaxf(mx[4], b.x); mx[5] = fmaxf(mx[5], b.y);
    mx[6] = fmaxf(mx[6], b.z); mx[7] = fmaxf(mx[7], b.w);
  }
  __shared__ unsigned bm[8];
  if (threadIdx.x < 8) bm[threadIdx.x] = 0u;
  __syncthreads();
  #pragma unroll
  for (int h = 0; h < 8; h++) atomicMax(&bm[h], fkey(mx[h]));
  __syncthreads();
  if (threadIdx.x < 8) atomicMax(&Mkey[threadIdx.x], bm[threadIdx.x]);
}

// ---------- att0 numerator/denominator partials (v in bf16) ----------
__global__ void sumk(const float* __restrict__ lb, const short* __restrict__ v,
                     const unsigned* __restrict__ Mkey,
                     float* __restrict__ P, float* __restrict__ S)
{
  int tid = threadIdx.x; int h = tid >> 5;
  float Mh = fdec(Mkey[h]);
  float pa = 0.f, sa = 0.f;
  for (int n = blockIdx.x; n < N_NODES; n += gridDim.x) {
    float w = expf(lb[n*16 + h] - Mh);
    pa = fmaf(w, bf2f(v[(size_t)n*256 + tid]), pa);
    sa += w;
  }
  atomicAdd(&P[tid], pa);
  if ((tid & 31) == 0) atomicAdd(&S[h], sa);
}

// ---------- PMA segment softmax + weighted V aggregation (wave per segment, bf16 v) ----------
__global__ __launch_bounds__(256) void aggk(
  const int* __restrict__ offA, const int* __restrict__ cnt,
  const int* __restrict__ ent, const int* __restrict__ eidx,
  const float* __restrict__ lb, const short* __restrict__ v,
  short* __restrict__ out)
{
  int g = blockIdx.x*4 + (threadIdx.x >> 6);
  if (g >= N_EDGES) return;
  int lane = threadIdx.x & 63;
  int h = lane >> 3;
  int co = lane*4;
  int base = offA[g], n = cnt[g];
  float m = -INFINITY, s = 0.f;
  float ax = 0.f, ay = 0.f, az = 0.f, aw = 0.f;
  for (int i = 0; i < n; i++) {
    int src = eidx[ent[base + i]];
    float ar = lb[src*16 + 8 + h];
    float a = (ar > 0.f) ? ar : 0.2f*ar;
    float mn = fmaxf(m, a);
    float sc = expf(m - mn);
    float p  = expf(a - mn);
    s = s*sc + p;
    bf16x4 vv = *(const bf16x4*)(v + (size_t)src*256 + co);
    ax = ax*sc + p*bf2f(vv[0]); ay = ay*sc + p*bf2f(vv[1]);
    az = az*sc + p*bf2f(vv[2]); aw = aw*sc + p*bf2f(vv[3]);
    m = mn;
  }
  float inv = 1.f/(s + 1e-16f);
  bf16x4 o4;
  o4[0] = f2bf(ax*inv); o4[1] = f2bf(ay*inv);
  o4[2] = f2bf(az*inv); o4[3] = f2bf(aw*inv);
  *(bf16x4*)(out + (size_t)g*256 + co) = o4;
}

// ---------- finalize att0 and apply blk2 to the single att0 row ----------
__global__ void att0k(const float* __restrict__ P, const float* __restrict__ S,
                      const float* __restrict__ c20, const float* __restrict__ W1G2,
                      const float* __restrict__ m2w2, const float* __restrict__ m2b2,
                      float* __restrict__ att0b)
{
  __shared__ float a0[256], zs[256], Hs[256];
  __shared__ float part[4];
  __shared__ float stat[2];
  int c = threadIdx.x;
  float av = P[c] / S[c >> 5];
  a0[c] = av;
  float x = av;
  for (int o = 32; o > 0; o >>= 1) x += __shfl_down(x, o);
  if ((c & 63) == 0) part[c >> 6] = x;
  __syncthreads();
  if (c == 0) stat[0] = (part[0]+part[1]+part[2]+part[3])*(1.f/256.f);
  __syncthreads();
  float mu = stat[0];
  float d = av - mu;
  x = d*d;
  for (int o = 32; o > 0; o >>= 1) x += __shfl_down(x, o);
  if ((c & 63) == 0) part[c >> 6] = x;
  __syncthreads();
  if (c == 0) stat[1] = rsqrtf((part[0]+part[1]+part[2]+part[3])*(1.f/256.f) + 1e-5f);
  __syncthreads();
  zs[c] = (av - mu)*stat[1];
  __syncthreads();
  float acc = c20[c];
  for (int k = 0; k < 256; k++) acc = fmaf(zs[k], W1G2[k*256 + c], acc);
  Hs[c] = fmaxf(acc, 0.f);
  __syncthreads();
  float acc2 = m2b2[c];
  for (int k = 0; k < 256; k++) acc2 = fmaf(Hs[k], m2w2[k*256 + c], acc2);
  att0b[c] = a0[c] + acc2;
}

// ---------- launcher ----------
extern "C" void kernel_launch(void* const* d_in, const int* in_sizes, int n_in,
                              void* d_out, int out_size, void* d_ws, size_t ws_size,
                              hipStream_t stream)
{
  const float* x    = (const float*)d_in[0];
  const int*   nidx = (const int*)d_in[1];
  const int*   eidx = (const int*)d_in[2];
  const int*   eord = (const int*)d_in[3];
  const float* pe_q = (const float*)d_in[4];
  const float* qw1  = (const float*)d_in[5];
  const float* qb1  = (const float*)d_in[6];
  const float* qw2  = (const float*)d_in[7];
  const float* qb2  = (const float*)d_in[8];
  const float* kw   = (const float*)d_in[9];
  const float* kb   = (const float*)d_in[10];
  const float* vw   = (const float*)d_in[11];
  const float* vb   = (const float*)d_in[12];
  const float* m1w1 = (const float*)d_in[13];
  const float* m1b1 = (const float*)d_in[14];
  const float* m1w2 = (const float*)d_in[15];
  const float* m1b2 = (const float*)d_in[16];
  const float* m2w1 = (const float*)d_in[17];
  const float* m2b1 = (const float*)d_in[18];
  const float* m2w2 = (const float*)d_in[19];
  const float* m2b2 = (const float*)d_in[20];
  const float* m3w1 = (const float*)d_in[21];
  const float* m3b1 = (const float*)d_in[22];
  const float* m3w2 = (const float*)d_in[23];
  const float* m3b2 = (const float*)d_in[24];
  const float* ln1g = (const float*)d_in[25];
  const float* ln1b = (const float*)d_in[26];
  const float* ln2g = (const float*)d_in[27];
  const float* ln2b = (const float*)d_in[28];
  const float* ln3g = (const float*)d_in[29];
  const float* ln3b = (const float*)d_in[30];
  const float* pe2  = (const float*)d_in[31];
  const float* pe3  = (const float*)d_in[32];
  const float* pe_b = (const float*)d_in[33];
  const float* bw1  = (const float*)d_in[34];
  const float* bb1  = (const float*)d_in[35];
  const float* bw2  = (const float*)d_in[36];
  const float* bb2  = (const float*)d_in[37];

  float* out_v = (float*)d_out;                       // [N,256] f32 final
  float* out_e = out_v + (size_t)N_NODES*256;         // [E,256] f32 final

  float* ws = (float*)d_ws;
  size_t o = 0;
  short* vbf  = (short*)(ws + o); o += (size_t)N_NODES*128;   // v bf16 [N,256]
  short* aeb  = (short*)(ws + o); o += (size_t)N_EDGES*128;   // att1_e bf16 [E,256]
  float* lb    = ws + o; o += (size_t)N_NODES*16;
  float* W1G1  = ws + o; o += 65536;
  float* W1G2  = ws + o; o += 65536;
  float* W1G3  = ws + o; o += 65536;
  float* kwq   = ws + o; o += 4096;
  float* kqb   = ws + o; o += 256;
  float* biasT = ws + o; o += 11*256;
  float* u11   = ws + o; o += 256;
  float* u12   = ws + o; o += 256;
  float* u13   = ws + o; o += 256;
  float* c1v   = ws + o; o += 256;
  float* c2v   = ws + o; o += 256;
  float* c20v  = ws + o; o += 256;
  float* c3tab = ws + o; o += 11*256;
  float* att0b = ws + o; o += 256;
  float* Pacc  = ws + o; o += 256;
  float* Sacc  = ws + o; o += 256;
  unsigned* Mkey = (unsigned*)(ws + o); o += 256;
  int* cnt  = (int*)(ws + o); o += N_EDGES;
  int* offA = (int*)(ws + o); o += N_EDGES;
  int* curA = (int*)(ws + o); o += N_EDGES;
  int* ent  = (int*)(ws + o); o += N_NNZ;
  short* Wpall = (short*)(ws + o); o += 7*32768;      // 7 matrices, bf16 [n][k]
  short* Kqp   = (short*)(ws + o); o += 2048;         // kwq bf16 [16][256]
  (void)in_sizes; (void)n_in; (void)out_size; (void)ws_size;

  short* Wp_w1g1 = Wpall + 0*65536;
  short* Wp_w1g2 = Wpall + 1*65536;
  short* Wp_w1g3 = Wpall + 2*65536;
  short* Wp_m1w2 = Wpall + 3*65536;
  short* Wp_m2w2 = Wpall + 4*65536;
  short* Wp_m3w2 = Wpall + 5*65536;
  short* Wp_vw   = Wpall + 6*65536;

  const int GN = (N_NODES + 63)/64;   // 1563
  const int GE = (N_EDGES + 63)/64;   // 782

  prepk<<<17, 256, 0, stream>>>(ln1g, ln1b, m1w1, m1b1, ln2g, ln2b, m2w1, m2b1,
                                ln3g, ln3b, m3w1, m3b1, pe2, pe3,
                                pe_q, qw1, qb1, qw2, qb2, kw, kb,
                                pe_b, bw1, bb1, bw2, bb2,
                                W1G1, W1G2, W1G3, u11, u12, u13,
                                c1v, c2v, c20v, c3tab, kwq, kqb, biasT);
  packk<<<dim3(8, 8), 256, 0, stream>>>(W1G1, W1G2, W1G3, m1w2, m2w2, m3w2, vw, Wpall, kwq, Kqp);
  initk<<<196, 256, 0, stream>>>(cnt, Pacc, Sacc, Mkey);
  countk<<<(N_NNZ + 255)/256, 256, 0, stream>>>(nidx, cnt);

  // x -> x1 -> {v bf16, logits}
  fusedAk<<<GN, 512, 0, stream>>>(x, Wp_w1g1, u11, c1v, Wp_m1w2, m1b2,
                                  Wp_vw, vb, Kqp, kqb, vbf, lb, N_NODES);

  maxk<<<256, 256, 0, stream>>>(lb, Mkey);
  sumk<<<1024, 256, 0, stream>>>(lb, vbf, Mkey, Pacc, Sacc);

  scank<<<1, 1024, 0, stream>>>(cnt, offA, curA);
  fillk<<<(N_NNZ + 255)/256, 256, 0, stream>>>(nidx, curA, ent);
  aggk<<<N_EDGES/4, 256, 0, stream>>>(offA, cnt, ent, eidx, lb, vbf, aeb);

  att0k<<<1, 256, 0, stream>>>(Pacc, Sacc, c20v, W1G2, m2w2, m2b2, att0b);

  // node path: fused blk2+blk3
  fused2k<<<GN, 512, 0, stream>>>(vbf, out_v, N_NODES,
                                  Wp_w1g2, u12, c2v, Wp_m2w2, m2b2, att0b,
                                  Wp_w1g3, u13, c3tab + 256, nullptr,
                                  Wp_m3w2, m3b2, biasT + 256, nullptr);
  // edge path: fused blk2+blk3 with per-order c3/bias
  fused2k<<<GE, 512, 0, stream>>>(aeb, out_e, N_EDGES,
                                  Wp_w1g2, u12, c2v, Wp_m2w2, m2b2, att0b,
                                  Wp_w1g3, u13, c3tab, eord,
                                  Wp_m3w2, m3b2, biasT, eord);
}

// Round 9
// 1160.183 us; speedup vs baseline: 2.5073x; 1.0343x over previous
//
#include <hip/hip_runtime.h>
#include <math.h>

#define N_NODES 100000
#define N_EDGES 50000
#define N_NNZ   600000

typedef __attribute__((ext_vector_type(8))) short bf16x8;
typedef __attribute__((ext_vector_type(4))) short bf16x4;
typedef __attribute__((ext_vector_type(4))) float f32x4;

// ---------- helpers ----------
__device__ __forceinline__ unsigned fkey(float f){
  unsigned u = __float_as_uint(f);
  return (u & 0x80000000u) ? ~u : (u | 0x80000000u);
}
__device__ __forceinline__ float fdec(unsigned k){
  return (k & 0x80000000u) ? __uint_as_float(k ^ 0x80000000u) : __uint_as_float(~k);
}
__device__ __forceinline__ short f2bf(float f){
  unsigned u = __float_as_uint(f);
  unsigned r = u + 0x7FFFu + ((u >> 16) & 1u);   // RNE
  return (short)(r >> 16);
}
__device__ __forceinline__ float bf2f(short s){
  return __uint_as_float(((unsigned)(unsigned short)s) << 16);
}

// ---------- prep: weight folds, q/kwq, bias table, constant vectors ----------
__global__ void prepk(
  const float* __restrict__ ln1g, const float* __restrict__ ln1b,
  const float* __restrict__ m1w1, const float* __restrict__ m1b1,
  const float* __restrict__ ln2g, const float* __restrict__ ln2b,
  const float* __restrict__ m2w1, const float* __restrict__ m2b1,
  const float* __restrict__ ln3g, const float* __restrict__ ln3b,
  const float* __restrict__ m3w1, const float* __restrict__ m3b1,
  const float* __restrict__ pe2, const float* __restrict__ pe3,
  const float* __restrict__ pe_q, const float* __restrict__ qw1,
  const float* __restrict__ qb1, const float* __restrict__ qw2,
  const float* __restrict__ qb2, const float* __restrict__ kw,
  const float* __restrict__ kb,
  const float* __restrict__ pe_b, const float* __restrict__ bw1,
  const float* __restrict__ bb1, const float* __restrict__ bw2,
  const float* __restrict__ bb2,
  float* __restrict__ W1G1, float* __restrict__ W1G2, float* __restrict__ W1G3,
  float* __restrict__ u11, float* __restrict__ u12, float* __restrict__ u13,
  float* __restrict__ c1v, float* __restrict__ c2v, float* __restrict__ c20v,
  float* __restrict__ c3tab, float* __restrict__ kwq, float* __restrict__ kqb,
  float* __restrict__ biasT)
{
  const int b = blockIdx.x, tid = threadIdx.x;
  __shared__ float ps[11*256];
  if (b < 4) {
    for (int i = tid; i < 16384; i += 256) { int idx = b*16384 + i; W1G1[idx] = ln1g[idx>>8]*m1w1[idx]; }
  } else if (b < 8) {
    int bb = b-4;
    for (int i = tid; i < 16384; i += 256) { int idx = bb*16384 + i; W1G2[idx] = ln2g[idx>>8]*m2w1[idx]; }
  } else if (b < 12) {
    int bb = b-8;
    for (int i = tid; i < 16384; i += 256) { int idx = bb*16384 + i; W1G3[idx] = ln3g[idx>>8]*m3w1[idx]; }
  } else if (b == 12) {
    int c = tid; float su = 0.f, sc = 0.f;
    for (int k = 0; k < 256; k++) { float w = m1w1[k*256+c]; su += ln1g[k]*w; sc += ln1b[k]*w; }
    u11[c] = su; c1v[c] = m1b1[c] + sc;
  } else if (b == 13) {
    int c = tid; float su = 0.f, sl = 0.f, p0 = 0.f, p1 = 0.f;
    for (int k = 0; k < 256; k++) {
      float wl = m2w1[k*256+c], wh = m2w1[(256+k)*256+c];
      su += ln2g[k]*wl; sl += ln2b[k]*wl; p0 += pe2[k]*wh; p1 += pe2[256+k]*wh;
    }
    u12[c] = su; c2v[c] = m2b1[c] + sl + p1; c20v[c] = m2b1[c] + sl + p0;
  } else if (b == 14) {
    int c = tid; float su = 0.f, sl = 0.f;
    for (int k = 0; k < 256; k++) { float wl = m3w1[k*256+c]; su += ln3g[k]*wl; sl += ln3b[k]*wl; }
    u13[c] = su;
    float base3 = m3b1[c] + sl;
    for (int o = 0; o < 11; o++) {
      float acc = 0.f;
      for (int k = 0; k < 256; k++) acc += pe3[o*256+k]*m3w1[(256+k)*256+c];
      c3tab[o*256+c] = base3 + acc;
    }
  } else if (b == 15) {
    int j = tid;
    for (int r = 0; r < 2; r++) {
      float acc = qb1[j];
      for (int k = 0; k < 64; k++) acc += pe_q[r*64+k]*qw1[k*256+j];
      ps[r*256+j] = fmaxf(acc, 0.f);
    }
    __syncthreads();
    for (int r = 0; r < 2; r++) {
      float acc = qb2[j];
      for (int k = 0; k < 256; k++) acc += ps[r*256+k]*qw2[k*256+j];
      ps[512 + r*256 + j] = acc;
    }
    __syncthreads();
    {
      const float* q0 = &ps[512]; const float* q1 = &ps[768];
      int k = tid;
      for (int h = 0; h < 8; h++) {
        float s0 = 0.f, s1 = 0.f;
        for (int d = 0; d < 32; d++) {
          s0 += kw[k*512 + h*32 + d]       * q0[h*32+d];
          s1 += kw[k*512 + 256 + h*32 + d] * q1[h*32+d];
        }
        kwq[k*16+h]   = s0 * 0.17677669529663687f;  // 1/sqrt(32)
        kwq[k*16+8+h] = s1;
      }
      if (tid < 8) {
        float s0 = 0.f, s1 = 0.f;
        for (int d = 0; d < 32; d++) {
          s0 += kb[tid*32+d]     * q0[tid*32+d];
          s1 += kb[256+tid*32+d] * q1[tid*32+d];
        }
        kqb[tid]   = s0 * 0.17677669529663687f;
        kqb[8+tid] = s1;
      }
    }
  } else if (b == 16) {
    int j = tid;
    for (int o = 0; o < 11; o++) {
      float acc = bb1[j];
      for (int k = 0; k < 64; k++) acc += pe_b[o*64+k]*bw1[k*256+j];
      ps[o*256+j] = fmaxf(acc, 0.f);
    }
    __syncthreads();
    int c = tid;
    for (int o = 0; o < 11; o++) {
      float acc = bb2[c];
      for (int k = 0; k < 256; k++) acc += ps[o*256+k]*bw2[k*256+c];
      biasT[o*256+c] = acc;
    }
  }
}

// ---------- pack fp32 [k][n] -> bf16 [n][k]; y==7 packs kwq [256][16] -> [16][256] ----------
__global__ void packk(const float* __restrict__ s0, const float* __restrict__ s1,
                      const float* __restrict__ s2, const float* __restrict__ s3,
                      const float* __restrict__ s4, const float* __restrict__ s5,
                      const float* __restrict__ s6, short* __restrict__ dst,
                      const float* __restrict__ kwq, short* __restrict__ Kqp)
{
  if (blockIdx.y == 7) {
    int k0 = blockIdx.x*32;
    int j = threadIdx.x & 15, kk = k0 + (threadIdx.x >> 4)*2;
    Kqp[j*256 + kk]   = f2bf(kwq[kk*16 + j]);
    Kqp[j*256 + kk+1] = f2bf(kwq[(kk+1)*16 + j]);
    return;
  }
  const float* srcs[7] = {s0,s1,s2,s3,s4,s5,s6};
  const float* S = srcs[blockIdx.y];
  short* D = dst + (size_t)blockIdx.y*65536;
  int n = threadIdx.x;
  int k0 = blockIdx.x*32;
  short vb[32];
  #pragma unroll
  for (int i = 0; i < 32; i++) vb[i] = f2bf(S[(k0+i)*256 + n]);
  #pragma unroll
  for (int i = 0; i < 4; i++) *(bf16x8*)&D[n*256 + k0 + i*8] = *(bf16x8*)&vb[i*8];
}

// ---------- init scratch ----------
__global__ void initk(int* __restrict__ cnt, float* __restrict__ P,
                      float* __restrict__ S, unsigned* __restrict__ Mkey){
  int i = blockIdx.x*256 + threadIdx.x;
  if (i < N_EDGES) cnt[i] = 0;
  if (i < 256) P[i] = 0.f;
  if (i < 8) { S[i] = 0.f; Mkey[i] = 0u; }
}

// ---------- CSR build ----------
__global__ void countk(const int* __restrict__ nidx, int* __restrict__ cnt){
  int e = blockIdx.x*256 + threadIdx.x;
  if (e < N_NNZ) { int g = nidx[e]; if (g < N_EDGES) atomicAdd(&cnt[g], 1); }
}
__global__ void scank(const int* __restrict__ cnt, int* __restrict__ offA, int* __restrict__ curA){
  __shared__ int sh[1024];
  int tid = threadIdx.x;
  const int PER = (N_EDGES + 1023)/1024;
  int base = tid*PER;
  int s = 0;
  for (int i = 0; i < PER; i++) { int idx = base+i; if (idx < N_EDGES) s += cnt[idx]; }
  sh[tid] = s;
  __syncthreads();
  for (int d = 1; d < 1024; d <<= 1) {
    int v = (tid >= d) ? sh[tid-d] : 0;
    __syncthreads();
    sh[tid] += v;
    __syncthreads();
  }
  int run = (tid == 0) ? 0 : sh[tid-1];
  for (int i = 0; i < PER; i++) {
    int idx = base+i;
    if (idx < N_EDGES) { offA[idx] = run; curA[idx] = run; run += cnt[idx]; }
  }
}
__global__ void fillk(const int* __restrict__ nidx, int* __restrict__ curA, int* __restrict__ ent){
  int e = blockIdx.x*256 + threadIdx.x;
  if (e < N_NNZ) {
    int g = nidx[e];
    if (g < N_EDGES) { int p = atomicAdd(&curA[g], 1); ent[p] = e; }
  }
}

// ---------- 512-thread / 8-wave GEMM helpers ----------
// Wave wv owns cols [wv*32, wv*32+32); ct in {0,1}. acc[rt][ct] covers rows rt*16.., cols wv*32+ct*16..
__device__ __forceinline__ void gemm8(const char* tb, const short* __restrict__ Wp,
    int lr, int lk, int wv, f32x4 acc[4][2])
{
  const int swzA = (lr & 7) << 4;
  const short* w0 = Wp + (size_t)(wv*32 + lr)*256 + lk;
  const short* w1 = w0 + 16*256;
  #pragma unroll
  for (int ks = 0; ks < 8; ks++) {
    bf16x8 a[4];
    #pragma unroll
    for (int rt = 0; rt < 4; rt++)
      a[rt] = *(const bf16x8*)(tb + (((rt*16 + lr)*512 + ks*64 + lk*2) ^ swzA));
    bf16x8 b0 = *(const bf16x8*)(w0 + ks*32);
    bf16x8 b1 = *(const bf16x8*)(w1 + ks*32);
    #pragma unroll
    for (int rt = 0; rt < 4; rt++) {
      acc[rt][0] = __builtin_amdgcn_mfma_f32_16x16x32_bf16(a[rt], b0, acc[rt][0], 0, 0, 0);
      acc[rt][1] = __builtin_amdgcn_mfma_f32_16x16x32_bf16(a[rt], b1, acc[rt][1], 0, 0, 0);
    }
  }
}

__device__ __forceinline__ void zacc(f32x4 acc[4][2]){
  const f32x4 z = {0.f,0.f,0.f,0.f};
  #pragma unroll
  for (int rt = 0; rt < 4; rt++) { acc[rt][0] = z; acc[rt][1] = z; }
}

__device__ __forceinline__ void stats512(const char* tb, float2* red, float2* rowstat, int tid)
{
  int row = tid >> 3, q = tid & 7;
  int swz = (row & 7) << 4;
  float s = 0.f, s2 = 0.f;
  #pragma unroll
  for (int j = 0; j < 4; j++) {
    bf16x8 h = *(const bf16x8*)(tb + ((row*512 + (q*32 + j*8)*2) ^ swz));
    #pragma unroll
    for (int e = 0; e < 8; e++) { float f = bf2f(h[e]); s += f; s2 += f*f; }
  }
  red[tid] = make_float2(s, s2);
  __syncthreads();
  if (tid < 64) {
    float ss = 0.f, ss2 = 0.f;
    #pragma unroll
    for (int k = 0; k < 8; k++) { float2 p = red[tid*8+k]; ss += p.x; ss2 += p.y; }
    float mu = ss * (1.f/256.f);
    float var = fmaxf(ss2*(1.f/256.f) - mu*mu, 0.f);
    rowstat[tid] = make_float2(mu, rsqrtf(var + 1e-5f));
  }
  __syncthreads();
}

__device__ __forceinline__ void epiH512(char* outb, const f32x4 acc[4][2],
    const float2* rowstat, const float* __restrict__ u, const float* __restrict__ cvec,
    const int* __restrict__ cidx, int row0, int nrows, int lr, int wv, int rb)
{
  float uv0 = u[wv*32 + lr], uv1 = u[wv*32 + 16 + lr];
  const int j0 = wv*32 + lr, j1 = j0 + 16;
  #pragma unroll
  for (int rt = 0; rt < 4; rt++) {
    #pragma unroll
    for (int r = 0; r < 4; r++) {
      int rl = rt*16 + rb + r;
      float2 st = rowstat[rl];
      const float* cb = cvec;
      if (cidx != nullptr) {
        int gr = row0 + rl;
        cb = cvec + (size_t)((gr < nrows) ? cidx[gr] : 0)*256;
      }
      int swz = (rl & 7) << 4;
      float h0 = fmaxf(st.y*(acc[rt][0][r] - st.x*uv0) + cb[j0], 0.f);
      float h1 = fmaxf(st.y*(acc[rt][1][r] - st.x*uv1) + cb[j1], 0.f);
      *(short*)(outb + ((rl*512 + j0*2) ^ swz)) = f2bf(h0);
      *(short*)(outb + ((rl*512 + j1*2) ^ swz)) = f2bf(h1);
    }
  }
}

// ---------- fused A: x -> x1 -> {v bf16, logits f32} ----------
__global__ __launch_bounds__(512, 2) void fusedAk(
  const float* __restrict__ x,
  const short* __restrict__ Wp1, const float* __restrict__ u1, const float* __restrict__ c1,
  const short* __restrict__ Wp2, const float* __restrict__ b2,
  const short* __restrict__ Wpv, const float* __restrict__ vb,
  const short* __restrict__ Kqp, const float* __restrict__ kqb,
  short* __restrict__ vout, float* __restrict__ lb, int nrows)
{
  __shared__ __align__(16) char smem[65536];
  __shared__ float2 red[512];
  __shared__ float2 rowstat[64];
  char* tA = smem;
  char* tB = smem + 32768;
  const int tid = threadIdx.x;
  const int wv = tid >> 6, lane = tid & 63;
  const int lr = lane & 15, lk = (lane >> 4)*8, rb = (lane >> 4)*4;
  const int row0 = blockIdx.x * 64;
  const int j0 = wv*32 + lr, j1 = j0 + 16;

  { // stage x f32 -> bf16 tA (swizzled)
    int row = tid >> 3, c0 = (tid & 7)*32;
    bool ok = (row0 + row < nrows);
    const float* sp = x + (size_t)(row0+row)*256 + c0;
    int swz = (row & 7) << 4;
    #pragma unroll
    for (int j = 0; j < 4; j++) {
      float4 f0 = ok ? *(const float4*)(sp + j*8)     : make_float4(0,0,0,0);
      float4 f1 = ok ? *(const float4*)(sp + j*8 + 4) : make_float4(0,0,0,0);
      bf16x8 h;
      h[0]=f2bf(f0.x); h[1]=f2bf(f0.y); h[2]=f2bf(f0.z); h[3]=f2bf(f0.w);
      h[4]=f2bf(f1.x); h[5]=f2bf(f1.y); h[6]=f2bf(f1.z); h[7]=f2bf(f1.w);
      *(bf16x8*)(tA + ((row*512 + (c0+j*8)*2) ^ swz)) = h;
    }
  }
  __syncthreads();
  stats512(tA, red, rowstat, tid);

  f32x4 acc[4][2];
  zacc(acc);
  gemm8(tA, Wp1, lr, lk, wv, acc);
  epiH512(tB, acc, rowstat, u1, c1, nullptr, row0, nrows, lr, wv, rb);
  __syncthreads();

  zacc(acc);
  gemm8(tB, Wp2, lr, lk, wv, acc);
  { // epi2: x1 = x(f32, re-read L2-hot) + acc + b2 -> bf16 tA
    float bv0 = b2[j0], bv1 = b2[j1];
    #pragma unroll
    for (int rt = 0; rt < 4; rt++) {
      #pragma unroll
      for (int r = 0; r < 4; r++) {
        int rl = rt*16 + rb + r;
        int gr = row0 + rl;
        bool ok = gr < nrows;
        const float* xp = x + (size_t)gr*256;
        int swz = (rl & 7) << 4;
        float x0 = ok ? xp[j0] : 0.f;
        float x1v = ok ? xp[j1] : 0.f;
        *(short*)(tA + ((rl*512 + j0*2) ^ swz)) = f2bf(x0 + acc[rt][0][r] + bv0);
        *(short*)(tA + ((rl*512 + j1*2) ^ swz)) = f2bf(x1v + acc[rt][1][r] + bv1);
      }
    }
  }
  __syncthreads();

  zacc(acc);
  gemm8(tA, Wpv, lr, lk, wv, acc);

  // logit GEMM on waves 0-3 (rows wv*16..+15)
  f32x4 aq = {0.f,0.f,0.f,0.f};
  if (wv < 4) {
    int arow = wv*16 + lr;
    int swzq = (lr & 7) << 4;
    #pragma unroll
    for (int ks = 0; ks < 8; ks++) {
      bf16x8 a = *(const bf16x8*)(tA + ((arow*512 + ks*64 + lk*2) ^ swzq));
      bf16x8 b = *(const bf16x8*)(Kqp + lr*256 + ks*32 + lk);
      aq = __builtin_amdgcn_mfma_f32_16x16x32_bf16(a, b, aq, 0, 0, 0);
    }
  }

  { // v fragments -> tB (linear bf16 [64][256])
    float vb0 = vb[j0], vb1 = vb[j1];
    short* tv = (short*)tB;
    #pragma unroll
    for (int rt = 0; rt < 4; rt++) {
      #pragma unroll
      for (int r = 0; r < 4; r++) {
        int rl = rt*16 + rb + r;
        tv[rl*256 + j0] = f2bf(acc[rt][0][r] + vb0);
        tv[rl*256 + j1] = f2bf(acc[rt][1][r] + vb1);
      }
    }
  }
  __syncthreads();
  { // coalesced v store
    const short* tv = (const short*)tB;
    #pragma unroll
    for (int i = 0; i < 4; i++) {
      int s = i*512 + tid;
      int row = s >> 5, gr = row0 + row;
      if (gr < nrows)
        *(bf16x8*)&vout[(size_t)gr*256 + (s & 31)*8] = *(const bf16x8*)&tv[(size_t)s*8];
    }
  }
  if (wv < 4) { // lb store
    float kq = kqb[lr];
    #pragma unroll
    for (int r = 0; r < 4; r++) {
      int gr = row0 + wv*16 + rb + r;
      if (gr < nrows) lb[(size_t)gr*16 + lr] = aq[r] + kq;
    }
  }
}

// ---------- fused blk2+blk3 (node & edge paths) ----------
__global__ __launch_bounds__(512, 2) void fused2k(
  const short* __restrict__ srcb, float* __restrict__ dst, int nrows,
  const short* __restrict__ Wp21, const float* __restrict__ u2, const float* __restrict__ c2,
  const short* __restrict__ Wp22, const float* __restrict__ b22, const float* __restrict__ add2,
  const short* __restrict__ Wp31, const float* __restrict__ u3, const float* __restrict__ c3, const int* __restrict__ c3idx,
  const short* __restrict__ Wp32, const float* __restrict__ b32, const float* __restrict__ add3, const int* __restrict__ a3idx)
{
  __shared__ __align__(16) char smem[65536];
  __shared__ float2 red[512];
  __shared__ float2 rowstat[64];
  char* tA = smem;
  char* tB = smem + 32768;
  const int tid = threadIdx.x;
  const int wv = tid >> 6, lane = tid & 63;
  const int lr = lane & 15, lk = (lane >> 4)*8, rb = (lane >> 4)*4;
  const int row0 = blockIdx.x * 64;
  const int j0 = wv*32 + lr, j1 = j0 + 16;

  { // stage src bf16 -> tA (swizzled)
    int row = tid >> 3, c0 = (tid & 7)*32;
    bool ok = (row0 + row < nrows);
    const short* sp = srcb + (size_t)(row0+row)*256 + c0;
    int swz = (row & 7) << 4;
    const bf16x8 zz = {0,0,0,0,0,0,0,0};
    #pragma unroll
    for (int j = 0; j < 4; j++) {
      bf16x8 h = ok ? *(const bf16x8*)(sp + j*8) : zz;
      *(bf16x8*)(tA + ((row*512 + (c0+j*8)*2) ^ swz)) = h;
    }
  }
  __syncthreads();
  stats512(tA, red, rowstat, tid);

  f32x4 acc[4][2];
  zacc(acc);
  gemm8(tA, Wp21, lr, lk, wv, acc);
  epiH512(tB, acc, rowstat, u2, c2, nullptr, row0, nrows, lr, wv, rb);
  __syncthreads();

  zacc(acc);
  gemm8(tB, Wp22, lr, lk, wv, acc);

  f32x4 t2a[4], t2b[4];   // f32 residual, 32 regs total
  { // epi2: t2 = v(tA) + acc + b22 + add2; keep f32, write bf16 -> tA
    float bv0 = b22[j0], bv1 = b22[j1];
    float av0 = add2[j0], av1 = add2[j1];
    #pragma unroll
    for (int rt = 0; rt < 4; rt++) {
      #pragma unroll
      for (int r = 0; r < 4; r++) {
        int rl = rt*16 + rb + r;
        int swz = (rl & 7) << 4;
        float v0 = bf2f(*(const short*)(tA + ((rl*512 + j0*2) ^ swz)));
        float v1 = bf2f(*(const short*)(tA + ((rl*512 + j1*2) ^ swz)));
        float t0 = v0 + acc[rt][0][r] + bv0 + av0;
        float t1 = v1 + acc[rt][1][r] + bv1 + av1;
        t2a[rt][r] = t0; t2b[rt][r] = t1;
        *(short*)(tA + ((rl*512 + j0*2) ^ swz)) = f2bf(t0);
        *(short*)(tA + ((rl*512 + j1*2) ^ swz)) = f2bf(t1);
      }
    }
  }
  __syncthreads();
  stats512(tA, red, rowstat, tid);

  zacc(acc);
  gemm8(tA, Wp31, lr, lk, wv, acc);
  epiH512(tB, acc, rowstat, u3, c3, c3idx, row0, nrows, lr, wv, rb);
  __syncthreads();

  zacc(acc);
  gemm8(tB, Wp32, lr, lk, wv, acc);
  __syncthreads();   // all tB reads done before smemF overwrite

  { // epi4 -> f32 staging in smem (full 64KB), then coalesced store
    float* smemF = (float*)smem;
    float bv0 = b32[j0], bv1 = b32[j1];
    #pragma unroll
    for (int rt = 0; rt < 4; rt++) {
      #pragma unroll
      for (int r = 0; r < 4; r++) {
        int rl = rt*16 + rb + r;
        int gr = row0 + rl;
        int ai = (a3idx != nullptr && gr < nrows) ? a3idx[gr] : 0;
        const float* ap = add3 + (size_t)ai*256;
        smemF[rl*256 + j0] = t2a[rt][r] + acc[rt][0][r] + bv0 + ap[j0];
        smemF[rl*256 + j1] = t2b[rt][r] + acc[rt][1][r] + bv1 + ap[j1];
      }
    }
    __syncthreads();
    #pragma unroll
    for (int i = 0; i < 8; i++) {
      int s = i*512 + tid;
      int row = s >> 6, gr = row0 + row;
      if (gr < nrows)
        *(float4*)&dst[(size_t)gr*256 + (s & 63)*4] = *(const float4*)&smemF[(size_t)s*4];
    }
  }
}

// ---------- global softmax max over N (per head) ----------
__global__ void maxk(const float* __restrict__ lb, unsigned* __restrict__ Mkey){
  float mx[8];
  #pragma unroll
  for (int h = 0; h < 8; h++) mx[h] = -INFINITY;
  for (int n = blockIdx.x*256 + threadIdx.x; n < N_NODES; n += 65536) {
    float4 a = *(const float4*)&lb[n*16];
    float4 b = *(const float4*)&lb[n*16+4];
    mx[0] = fmaxf(mx[0], a.x); mx[1] = fmaxf(mx[1], a.y);
    mx[2] = fmaxf(mx[2], a.z); mx[3] = fmaxf(mx[3], a.w);
    mx[4] = fmaxf(mx[4], b.x); mx[5] = fmaxf(mx[5], b.y);
    mx[6] = fmaxf(mx[6], b.z); mx[7] = fmaxf(mx[7], b.w);
  }
  __shared__ unsigned bm[8];
  if (threadIdx.x < 8) bm[threadIdx.x] = 0u;
  __syncthreads();
  #pragma unroll
  for (int h = 0; h < 8; h++) atomicMax(&bm[h], fkey(mx[h]));
  __syncthreads();
  if (threadIdx.x < 8) atomicMax(&Mkey[threadIdx.x], bm[threadIdx.x]);
}

// ---------- att0 numerator/denominator partials (v in bf16) ----------
__global__ void sumk(const float* __restrict__ lb, const short* __restrict__ v,
                     const unsigned* __restrict__ Mkey,
                     float* __restrict__ P, float* __restrict__ S)
{
  int tid = threadIdx.x; int h = tid >> 5;
  float Mh = fdec(Mkey[h]);
  float pa = 0.f, sa = 0.f;
  for (int n = blockIdx.x; n < N_NODES; n += gridDim.x) {
    float w = expf(lb[n*16 + h] - Mh);
    pa = fmaf(w, bf2f(v[(size_t)n*256 + tid]), pa);
    sa += w;
  }
  atomicAdd(&P[tid], pa);
  if ((tid & 31) == 0) atomicAdd(&S[h], sa);
}

// ---------- PMA segment softmax + weighted V aggregation (wave per segment, bf16 v) ----------
__global__ __launch_bounds__(256) void aggk(
  const int* __restrict__ offA, const int* __restrict__ cnt,
  const int* __restrict__ ent, const int* __restrict__ eidx,
  const float* __restrict__ lb, const short* __restrict__ v,
  short* __restrict__ out)
{
  int g = blockIdx.x*4 + (threadIdx.x >> 6);
  if (g >= N_EDGES) return;
  int lane = threadIdx.x & 63;
  int h = lane >> 3;
  int co = lane*4;
  int base = offA[g], n = cnt[g];
  float m = -INFINITY, s = 0.f;
  float ax = 0.f, ay = 0.f, az = 0.f, aw = 0.f;
  for (int i = 0; i < n; i++) {
    int src = eidx[ent[base + i]];
    float ar = lb[src*16 + 8 + h];
    float a = (ar > 0.f) ? ar : 0.2f*ar;
    float mn = fmaxf(m, a);
    float sc = expf(m - mn);
    float p  = expf(a - mn);
    s = s*sc + p;
    bf16x4 vv = *(const bf16x4*)(v + (size_t)src*256 + co);
    ax = ax*sc + p*bf2f(vv[0]); ay = ay*sc + p*bf2f(vv[1]);
    az = az*sc + p*bf2f(vv[2]); aw = aw*sc + p*bf2f(vv[3]);
    m = mn;
  }
  float inv = 1.f/(s + 1e-16f);
  bf16x4 o4;
  o4[0] = f2bf(ax*inv); o4[1] = f2bf(ay*inv);
  o4[2] = f2bf(az*inv); o4[3] = f2bf(aw*inv);
  *(bf16x4*)(out + (size_t)g*256 + co) = o4;
}

// ---------- finalize att0 and apply blk2 to the single att0 row ----------
__global__ void att0k(const float* __restrict__ P, const float* __restrict__ S,
                      const float* __restrict__ c20, const float* __restrict__ W1G2,
                      const float* __restrict__ m2w2, const float* __restrict__ m2b2,
                      float* __restrict__ att0b)
{
  __shared__ float a0[256], zs[256], Hs[256];
  __shared__ float part[4];
  __shared__ float stat[2];
  int c = threadIdx.x;
  float av = P[c] / S[c >> 5];
  a0[c] = av;
  float x = av;
  for (int o = 32; o > 0; o >>= 1) x += __shfl_down(x, o);
  if ((c & 63) == 0) part[c >> 6] = x;
  __syncthreads();
  if (c == 0) stat[0] = (part[0]+part[1]+part[2]+part[3])*(1.f/256.f);
  __syncthreads();
  float mu = stat[0];
  float d = av - mu;
  x = d*d;
  for (int o = 32; o > 0; o >>= 1) x += __shfl_down(x, o);
  if ((c & 63) == 0) part[c >> 6] = x;
  __syncthreads();
  if (c == 0) stat[1] = rsqrtf((part[0]+part[1]+part[2]+part[3])*(1.f/256.f) + 1e-5f);
  __syncthreads();
  zs[c] = (av - mu)*stat[1];
  __syncthreads();
  float acc = c20[c];
  for (int k = 0; k < 256; k++) acc = fmaf(zs[k], W1G2[k*256 + c], acc);
  Hs[c] = fmaxf(acc, 0.f);
  __syncthreads();
  float acc2 = m2b2[c];
  for (int k = 0; k < 256; k++) acc2 = fmaf(Hs[k], m2w2[k*256 + c], acc2);
  att0b[c] = a0[c] + acc2;
}

// ---------- launcher ----------
extern "C" void kernel_launch(void* const* d_in, const int* in_sizes, int n_in,
                              void* d_out, int out_size, void* d_ws, size_t ws_size,
                              hipStream_t stream)
{
  const float* x    = (const float*)d_in[0];
  const int*   nidx = (const int*)d_in[1];
  const int*   eidx = (const int*)d_in[2];
  const int*   eord = (const int*)d_in[3];
  const float* pe_q = (const float*)d_in[4];
  const float* qw1  = (const float*)d_in[5];
  const float* qb1  = (const float*)d_in[6];
  const float* qw2  = (const float*)d_in[7];
  const float* qb2  = (const float*)d_in[8];
  const float* kw   = (const float*)d_in[9];
  const float* kb   = (const float*)d_in[10];
  const float* vw   = (const float*)d_in[11];
  const float* vb   = (const float*)d_in[12];
  const float* m1w1 = (const float*)d_in[13];
  const float* m1b1 = (const float*)d_in[14];
  const float* m1w2 = (const float*)d_in[15];
  const float* m1b2 = (const float*)d_in[16];
  const float* m2w1 = (const float*)d_in[17];
  const float* m2b1 = (const float*)d_in[18];
  const float* m2w2 = (const float*)d_in[19];
  const float* m2b2 = (const float*)d_in[20];
  const float* m3w1 = (const float*)d_in[21];
  const float* m3b1 = (const float*)d_in[22];
  const float* m3w2 = (const float*)d_in[23];
  const float* m3b2 = (const float*)d_in[24];
  const float* ln1g = (const float*)d_in[25];
  const float* ln1b = (const float*)d_in[26];
  const float* ln2g = (const float*)d_in[27];
  const float* ln2b = (const float*)d_in[28];
  const float* ln3g = (const float*)d_in[29];
  const float* ln3b = (const float*)d_in[30];
  const float* pe2  = (const float*)d_in[31];
  const float* pe3  = (const float*)d_in[32];
  const float* pe_b = (const float*)d_in[33];
  const float* bw1  = (const float*)d_in[34];
  const float* bb1  = (const float*)d_in[35];
  const float* bw2  = (const float*)d_in[36];
  const float* bb2  = (const float*)d_in[37];

  float* out_v = (float*)d_out;                       // [N,256] f32 final
  float* out_e = out_v + (size_t)N_NODES*256;         // [E,256] f32 final

  float* ws = (float*)d_ws;
  size_t o = 0;
  short* vbf  = (short*)(ws + o); o += (size_t)N_NODES*128;   // v bf16 [N,256]
  short* aeb  = (short*)(ws + o); o += (size_t)N_EDGES*128;   // att1_e bf16 [E,256]
  float* lb    = ws + o; o += (size_t)N_NODES*16;
  float* W1G1  = ws + o; o += 65536;
  float* W1G2  = ws + o; o += 65536;
  float* W1G3  = ws + o; o += 65536;
  float* kwq   = ws + o; o += 4096;
  float* kqb   = ws + o; o += 256;
  float* biasT = ws + o; o += 11*256;
  float* u11   = ws + o; o += 256;
  float* u12   = ws + o; o += 256;
  float* u13   = ws + o; o += 256;
  float* c1v   = ws + o; o += 256;
  float* c2v   = ws + o; o += 256;
  float* c20v  = ws + o; o += 256;
  float* c3tab = ws + o; o += 11*256;
  float* att0b = ws + o; o += 256;
  float* Pacc  = ws + o; o += 256;
  float* Sacc  = ws + o; o += 256;
  unsigned* Mkey = (unsigned*)(ws + o); o += 256;
  int* cnt  = (int*)(ws + o); o += N_EDGES;
  int* offA = (int*)(ws + o); o += N_EDGES;
  int* curA = (int*)(ws + o); o += N_EDGES;
  int* ent  = (int*)(ws + o); o += N_NNZ;
  short* Wpall = (short*)(ws + o); o += 7*32768;      // 7 matrices, bf16 [n][k]
  short* Kqp   = (short*)(ws + o); o += 2048;         // kwq bf16 [16][256]
  (void)in_sizes; (void)n_in; (void)out_size; (void)ws_size;

  short* Wp_w1g1 = Wpall + 0*65536;
  short* Wp_w1g2 = Wpall + 1*65536;
  short* Wp_w1g3 = Wpall + 2*65536;
  short* Wp_m1w2 = Wpall + 3*65536;
  short* Wp_m2w2 = Wpall + 4*65536;
  short* Wp_m3w2 = Wpall + 5*65536;
  short* Wp_vw   = Wpall + 6*65536;

  const int GN = (N_NODES + 63)/64;   // 1563
  const int GE = (N_EDGES + 63)/64;   // 782

  prepk<<<17, 256, 0, stream>>>(ln1g, ln1b, m1w1, m1b1, ln2g, ln2b, m2w1, m2b1,
                                ln3g, ln3b, m3w1, m3b1, pe2, pe3,
                                pe_q, qw1, qb1, qw2, qb2, kw, kb,
                                pe_b, bw1, bb1, bw2, bb2,
                                W1G1, W1G2, W1G3, u11, u12, u13,
                                c1v, c2v, c20v, c3tab, kwq, kqb, biasT);
  packk<<<dim3(8, 8), 256, 0, stream>>>(W1G1, W1G2, W1G3, m1w2, m2w2, m3w2, vw, Wpall, kwq, Kqp);
  initk<<<196, 256, 0, stream>>>(cnt, Pacc, Sacc, Mkey);
  countk<<<(N_NNZ + 255)/256, 256, 0, stream>>>(nidx, cnt);

  // x -> x1 -> {v bf16, logits}
  fusedAk<<<GN, 512, 0, stream>>>(x, Wp_w1g1, u11, c1v, Wp_m1w2, m1b2,
                                  Wp_vw, vb, Kqp, kqb, vbf, lb, N_NODES);

  maxk<<<256, 256, 0, stream>>>(lb, Mkey);
  sumk<<<1024, 256, 0, stream>>>(lb, vbf, Mkey, Pacc, Sacc);

  scank<<<1, 1024, 0, stream>>>(cnt, offA, curA);
  fillk<<<(N_NNZ + 255)/256, 256, 0, stream>>>(nidx, curA, ent);
  aggk<<<N_EDGES/4, 256, 0, stream>>>(offA, cnt, ent, eidx, lb, vbf, aeb);

  att0k<<<1, 256, 0, stream>>>(Pacc, Sacc, c20v, W1G2, m2w2, m2b2, att0b);

  // node path: fused blk2+blk3
  fused2k<<<GN, 512, 0, stream>>>(vbf, out_v, N_NODES,
                                  Wp_w1g2, u12, c2v, Wp_m2w2, m2b2, att0b,
                                  Wp_w1g3, u13, c3tab + 256, nullptr,
                                  Wp_m3w2, m3b2, biasT + 256, nullptr);
  // edge path: fused blk2+blk3 with per-order c3/bias
  fused2k<<<GE, 512, 0, stream>>>(aeb, out_e, N_EDGES,
                                  Wp_w1g2, u12, c2v, Wp_m2w2, m2b2, att0b,
                                  Wp_w1g3, u13, c3tab, eord,
                                  Wp_m3w2, m3b2, biasT, eord);
}